// Round 3
// baseline (29157.288 us; speedup 1.0000x reference)
//
#include <hip/hip_runtime.h>
#include <math.h>

namespace {

constexpr int nB = 16, nR = 400, nT = 400, nH = 8, nQ = 64;
constexpr int BH = nB * nH;   // 128
constexpr int HQ = nH * nQ;   // 512
constexpr int KP = 416;       // padded K/N for bf16 GCN GEMM (13 x 32)

typedef __attribute__((ext_vector_type(8))) short short8;
typedef __attribute__((ext_vector_type(4))) float floatx4;

__device__ __forceinline__ unsigned short f2bf(float f) {
  unsigned int u = __float_as_uint(f);
  unsigned int r = (u + 0x7fffu + ((u >> 16) & 1u)) >> 16;
  return (unsigned short)r;
}

__device__ __forceinline__ void gload16(const void* g, void* l) {
  __builtin_amdgcn_global_load_lds(
      (const __attribute__((address_space(1))) unsigned int*)g,
      (__attribute__((address_space(3))) unsigned int*)l, 16, 0, 0);
}

// ---------------- generic fp32 GEMM: C = act(A@W + bias) ----------------
template<int BM, int BN, int BK, int TM, int TN, bool RELU>
__global__ __launch_bounds__(256) void gemm_k(
    const float* __restrict__ A, const float* __restrict__ W,
    const float* __restrict__ bias,
    float* C, int M, int N, int K)
{
  constexpr int NT = (BM / TM) * (BN / TN);
  static_assert(NT == 256, "block must be 256 threads");
  __shared__ float As[BK][BM + 4];
  __shared__ float Bs[BK][BN + 4];
  const int tid = threadIdx.x;
  const int bm = blockIdx.y * BM;
  const int bn = blockIdx.x * BN;
  const int tx = tid % (BN / TN);
  const int ty = tid / (BN / TN);
  const bool n4ok = ((N & 3) == 0);

  float acc[TM][TN];
#pragma unroll
  for (int i = 0; i < TM; ++i)
#pragma unroll
    for (int j = 0; j < TN; ++j) acc[i][j] = 0.f;

  for (int kt = 0; kt < K; kt += BK) {
#pragma unroll
    for (int i = 0; i < (BM * BK) / (NT * 4); ++i) {
      int flat = (tid + i * NT) * 4;
      int m = flat / BK;
      int k = flat % BK;
      float4 v = *(const float4*)(A + (size_t)(bm + m) * K + kt + k);
      As[k + 0][m] = v.x; As[k + 1][m] = v.y;
      As[k + 2][m] = v.z; As[k + 3][m] = v.w;
    }
#pragma unroll
    for (int i = 0; i < (BK * BN) / (NT * 4); ++i) {
      int flat = (tid + i * NT) * 4;
      int k = flat / BN;
      int n = flat % BN;
      int gn = bn + n;
      float4 v;
      if (n4ok && gn + 3 < N) {
        v = *(const float4*)(W + (size_t)(kt + k) * N + gn);
      } else {
        v.x = (gn + 0 < N) ? W[(size_t)(kt + k) * N + gn + 0] : 0.f;
        v.y = (gn + 1 < N) ? W[(size_t)(kt + k) * N + gn + 1] : 0.f;
        v.z = (gn + 2 < N) ? W[(size_t)(kt + k) * N + gn + 2] : 0.f;
        v.w = (gn + 3 < N) ? W[(size_t)(kt + k) * N + gn + 3] : 0.f;
      }
      *(float4*)&Bs[k][n] = v;
    }
    __syncthreads();
#pragma unroll
    for (int k = 0; k < BK; ++k) {
      float a[TM], b[TN];
#pragma unroll
      for (int i = 0; i < TM; i += 4)
        *(float4*)&a[i] = *(const float4*)&As[k][ty * TM + i];
#pragma unroll
      for (int j = 0; j < TN; j += 4)
        *(float4*)&b[j] = *(const float4*)&Bs[k][tx * TN + j];
#pragma unroll
      for (int i = 0; i < TM; ++i)
#pragma unroll
        for (int j = 0; j < TN; ++j) acc[i][j] += a[i] * b[j];
    }
    __syncthreads();
  }

#pragma unroll
  for (int i = 0; i < TM; ++i) {
    const int gm = bm + ty * TM + i;
    float* crow = C + (size_t)gm * N;
#pragma unroll
    for (int j = 0; j < TN; j += 4) {
      const int gn = bn + tx * TN + j;
      if (n4ok && gn + 3 < N) {
        float4 bv = *(const float4*)(bias + gn);
        float4 v;
        v.x = acc[i][j + 0] + bv.x; v.y = acc[i][j + 1] + bv.y;
        v.z = acc[i][j + 2] + bv.z; v.w = acc[i][j + 3] + bv.w;
        if (RELU) {
          v.x = fmaxf(v.x, 0.f); v.y = fmaxf(v.y, 0.f);
          v.z = fmaxf(v.z, 0.f); v.w = fmaxf(v.w, 0.f);
        }
        *(float4*)(crow + gn) = v;
      } else {
#pragma unroll
        for (int jj = 0; jj < 4; ++jj) {
          int gnn = gn + jj;
          if (gnn < N) {
            float v = acc[i][j + jj] + bias[gnn];
            if (RELU) v = fmaxf(v, 0.f);
            crow[gnn] = v;
          }
        }
      }
    }
  }
}

// ---------------- bf16 MFMA GEMM for GCN layers (BM=256, KP=416, slim-N) ------
// A(msg): [51200][416] bf16;  Bt: [416][416] bf16 n-major;  C(feats): [51200][400] f32
// C = relu(A@W + bias) + (first ? broadcast(x) : C)
__global__ __launch_bounds__(256) void gcn_gemm(
    const unsigned short* __restrict__ A,
    const unsigned short* __restrict__ Bt,
    const float* __restrict__ bias,
    float* __restrict__ C,
    const float* __restrict__ x, int first)
{
  __shared__ __align__(128) unsigned short As[256 * 32];  // 16 KB
  __shared__ __align__(128) unsigned short Bs[128 * 32];  //  8 KB

  const int tid = threadIdx.x;
  const int lane = tid & 63;
  const int wave = tid >> 6;
  const int bm = blockIdx.y * 256;
  const int bn = blockIdx.x * 128;
  const int wm = (wave & 1) * 128;        // m-half (128 rows)
  const int wn = (wave >> 1) * 64;        // n-half (64 cols)

  // number of live 16-col n-tiles for this wave (cols >= 400 are pad)
  int nimax = (400 - bn - wn + 15) >> 4;
  nimax = nimax < 0 ? 0 : (nimax > 4 ? 4 : nimax);

  floatx4 acc[8][4] = {};

  // staging: A rows [wave*64, wave*64+64), B rows [wave*32, wave*32+32)
  const int lrow = lane >> 2;          // 0..15
  const int lk = (lane & 3) * 8;       // shorts
  const unsigned short* Ag = A + (size_t)(bm + wave * 64 + lrow) * KP + lk;
  int br0 = bn + wave * 32 + lrow;      if (br0 > 415) br0 = 415;
  int br1 = bn + wave * 32 + 16 + lrow; if (br1 > 415) br1 = 415;
  const unsigned short* Bg0 = Bt + (size_t)br0 * KP + lk;
  const unsigned short* Bg1 = Bt + (size_t)br1 * KP + lk;

  const int fr = lane & 15;
  const int fkk = (lane >> 4) * 8;

  for (int kt = 0; kt < KP; kt += 32) {
#pragma unroll
    for (int i = 0; i < 4; ++i)
      gload16(Ag + (size_t)i * 16 * KP + kt, As + (wave * 4 + i) * 512);
    gload16(Bg0 + kt, Bs + (wave * 2) * 512);
    gload16(Bg1 + kt, Bs + (wave * 2 + 1) * 512);
    __syncthreads();

    short8 a[8], b[4];
#pragma unroll
    for (int mi = 0; mi < 8; ++mi)
      a[mi] = *(const short8*)(As + (wm + mi * 16 + fr) * 32 + fkk);
    for (int ni = 0; ni < nimax; ++ni)
      b[ni] = *(const short8*)(Bs + (wn + ni * 16 + fr) * 32 + fkk);
#pragma unroll
    for (int mi = 0; mi < 8; ++mi)
      for (int ni = 0; ni < nimax; ++ni)
        acc[mi][ni] = __builtin_amdgcn_mfma_f32_16x16x32_bf16(
            a[mi], b[ni], acc[mi][ni], 0, 0, 0);
    __syncthreads();
  }

  // epilogue: C/D layout col=lane&15, row=(lane>>4)*4+reg
  const int colb = bn + wn + (lane & 15);
  float bv[4];
  for (int ni = 0; ni < nimax; ++ni) bv[ni] = bias[colb + ni * 16];

#pragma unroll
  for (int mi = 0; mi < 8; ++mi) {
    const int row0 = bm + wm + mi * 16 + (lane >> 4) * 4;
#pragma unroll
    for (int r = 0; r < 4; ++r) {
      const int gr = row0 + r;
      float* crow = C + (size_t)gr * nT;
      const float* resrow;
      if (first) {
        const int bh = gr / nR;
        const int rr = gr - bh * nR;
        resrow = x + (size_t)(bh >> 3) * (nR * nT) + (size_t)rr * nT;
      } else {
        resrow = crow;
      }
      for (int ni = 0; ni < nimax; ++ni) {
        const int col = colb + ni * 16;
        crow[col] = fmaxf(acc[mi][ni][r] + bv[ni], 0.f) + resrow[col];
      }
    }
  }
}

// ---------------- W prep: Wt[i][n][k] = bf16(gcn_W[i][k][n]), zero-padded ------
__global__ void wprep_k(const float* __restrict__ W, unsigned short* __restrict__ Wt)
{
  __shared__ float t[32][33];
  const int i = blockIdx.z;
  const int k0 = blockIdx.x * 32;
  const int n0 = blockIdx.y * 32;
  const int tx = threadIdx.x, ty = threadIdx.y;   // 32 x 8
#pragma unroll
  for (int r = 0; r < 32; r += 8) {
    int k = k0 + ty + r, n = n0 + tx;
    t[ty + r][tx] = (k < nT && n < nT) ? W[(size_t)i * nT * nT + (size_t)k * nT + n] : 0.f;
  }
  __syncthreads();
#pragma unroll
  for (int r = 0; r < 32; r += 8) {
    int n = n0 + ty + r, k = k0 + tx;
    Wt[(size_t)i * KP * KP + (size_t)n * KP + k] = f2bf(t[tx][ty + r]);
  }
}

// ---------------- SE gate (gap == 1/R identically) -----------------------------
__global__ void gate_k(const float* __restrict__ w1, const float* __restrict__ b1,
                       const float* __restrict__ w2, const float* __restrict__ b2,
                       float* gate)
{
  if (threadIdx.x == 0 && blockIdx.x == 0) {
    float h1[4];
    const float gap = 1.0f / 400.0f;
#pragma unroll
    for (int i = 0; i < 4; ++i) {
      float s = b1[i];
      for (int h = 0; h < 8; ++h) s += gap * w1[h * 4 + i];
      h1[i] = fmaxf(s, 0.f);
    }
#pragma unroll
    for (int h = 0; h < 8; ++h) {
      float s = b2[h];
      for (int i = 0; i < 4; ++i) s += h1[i] * w2[i * 8 + h];
      gate[h] = 1.f / (1.f + expf(-s));
    }
  }
}

// ---------------- fused scores -> relu -> softmax -> gate -> stable-rank mask --
__global__ __launch_bounds__(256) void attn_k(
    const float* __restrict__ qk, const float* __restrict__ gate,
    float* __restrict__ adjval, int* __restrict__ adjcol)
{
  __shared__ float Qs[16][68];
  __shared__ float Ks[64][68];
  __shared__ float sc[16][404];

  const int tid = threadIdx.x;
  const int blk = blockIdx.x;
  const int bh = blk / 25;
  const int rt = (blk % 25) * 16;
  const int b = bh / nH;
  const int h = bh % nH;
  const float* qkb = qk + (size_t)b * nR * HQ + h * nQ;

  {
    int r = tid >> 4;
    int q = (tid & 15) << 2;
    *(float4*)&Qs[r][q] = *(const float4*)(qkb + (size_t)(rt + r) * HQ + q);
  }

  const int r0 = (tid & 7) * 2;
  const int s0 = (tid >> 3) * 2;

  for (int st = 0; st < 7; ++st) {
    const int sn = st * 64;
    const int cnt = (nR - sn < 64) ? (nR - sn) : 64;
    __syncthreads();
#pragma unroll
    for (int i = 0; i < 4; ++i) {
      int flat = (tid + i * 256) * 4;
      int j = flat >> 6;
      int q = flat & 63;
      if (j < cnt)
        *(float4*)&Ks[j][q] = *(const float4*)(qkb + (size_t)(sn + j) * HQ + q);
    }
    __syncthreads();
    float a00 = 0.f, a01 = 0.f, a10 = 0.f, a11 = 0.f;
#pragma unroll
    for (int q4 = 0; q4 < 16; ++q4) {
      float4 qa = *(const float4*)&Qs[r0][q4 * 4];
      float4 qb = *(const float4*)&Qs[r0 + 1][q4 * 4];
      float4 ka = *(const float4*)&Ks[s0][q4 * 4];
      float4 kb = *(const float4*)&Ks[s0 + 1][q4 * 4];
      a00 += qa.x * ka.x + qa.y * ka.y + qa.z * ka.z + qa.w * ka.w;
      a01 += qa.x * kb.x + qa.y * kb.y + qa.z * kb.z + qa.w * kb.w;
      a10 += qb.x * ka.x + qb.y * ka.y + qb.z * ka.z + qb.w * ka.w;
      a11 += qb.x * kb.x + qb.y * kb.y + qb.z * kb.z + qb.w * kb.w;
    }
    if (s0 < cnt) {
      sc[r0][sn + s0]     = fmaxf(a00 * 0.125f, 0.f);
      sc[r0 + 1][sn + s0] = fmaxf(a10 * 0.125f, 0.f);
    }
    if (s0 + 1 < cnt) {
      sc[r0][sn + s0 + 1]     = fmaxf(a01 * 0.125f, 0.f);
      sc[r0 + 1][sn + s0 + 1] = fmaxf(a11 * 0.125f, 0.f);
    }
  }
  __syncthreads();

  const int tr = tid >> 4;
  const int tl = tid & 15;
  float m = 0.f;
  for (int j = tl; j < nR; j += 16) m = fmaxf(m, sc[tr][j]);
#pragma unroll
  for (int o = 8; o > 0; o >>= 1) m = fmaxf(m, __shfl_xor(m, o));
  float ssum = 0.f;
  for (int j = tl; j < nR; j += 16) {
    float e = expf(sc[tr][j] - m);
    sc[tr][j] = e;
    ssum += e;
  }
#pragma unroll
  for (int o = 8; o > 0; o >>= 1) ssum += __shfl_xor(ssum, o);
  const float g = gate[h];
  for (int j = tl; j < nR; j += 16) sc[tr][j] = (sc[tr][j] / ssum) * g;
  __syncthreads();

  const int csp[6] = {0, 16, 17, 18, 19, 20};
  float vc[6];
#pragma unroll
  for (int i = 0; i < 6; ++i) vc[i] = sc[tr][csp[i]];
  int rk[6] = {0, 0, 0, 0, 0, 0};
  for (int j = tl; j < nR; j += 16) {
    float vj = sc[tr][j];
#pragma unroll
    for (int i = 0; i < 6; ++i)
      rk[i] += (vj < vc[i]) ? 1 : ((vj == vc[i] && j < csp[i]) ? 1 : 0);
  }
#pragma unroll
  for (int i = 0; i < 6; ++i)
#pragma unroll
    for (int o = 8; o > 0; o >>= 1) rk[i] += __shfl_xor(rk[i], o);

  if (tl == 0) {
    const int rg = rt + tr;
    const size_t base = ((size_t)bh * nR + rg) * 8;
    bool dup = false;
#pragma unroll
    for (int i = 0; i < 6; ++i) {
      int p = rk[i];
      adjcol[base + i] = p;
      adjval[base + i] = sc[tr][p];
      dup = dup || (p == rg);
    }
    adjcol[base + 6] = rg;
    adjval[base + 6] = dup ? 0.f : sc[tr][rg];
    adjcol[base + 7] = rg;
    adjval[base + 7] = 0.f;
  }
}

// ---------------- sparse msg via LDS-staged feats column-chunks ----------------
// grid (13, 128): (col-chunk, bh). Each block stages feats[bh][:, c0:c0+32] in
// LDS (+1 float4 row pad) and emits msg bf16 for those 32 (padded) columns.
__global__ __launch_bounds__(256) void spmsg_k(
    const int* __restrict__ adjcol, const float* __restrict__ adjval,
    const float* __restrict__ feats, const float* __restrict__ x, int first,
    unsigned short* __restrict__ msg)
{
  __shared__ float fs[400 * 36];   // 57.6 KB, row stride 36 floats (9 float4)

  const int tid = threadIdx.x;
  const int bh = blockIdx.y;
  const int c0 = blockIdx.x * 32;
  const float* src = first ? (x + (size_t)(bh >> 3) * (nR * nT))
                           : (feats + (size_t)bh * nR * nT);

  // stage: 400 rows x 8 float4 (cols >= 400 zero)
  for (int i = tid; i < 3200; i += 256) {
    const int r = i >> 3, c4 = i & 7;
    const int c = c0 + c4 * 4;
    float4 v = {0.f, 0.f, 0.f, 0.f};
    if (c < 400) v = *(const float4*)(src + (size_t)r * nT + c);
    *(float4*)&fs[r * 36 + c4 * 4] = v;
  }
  __syncthreads();

  const int* ac = adjcol + (size_t)bh * nR * 8;
  const float* av = adjval + (size_t)bh * nR * 8;
  for (int i = tid; i < 3200; i += 256) {
    const int r = i >> 3, c4 = i & 7;
    float4 acc = {0.f, 0.f, 0.f, 0.f};
#pragma unroll
    for (int j = 0; j < 7; ++j) {
      const int col = ac[r * 8 + j];
      const float val = av[r * 8 + j];
      float4 v = *(const float4*)&fs[col * 36 + c4 * 4];
      acc.x += val * v.x; acc.y += val * v.y;
      acc.z += val * v.z; acc.w += val * v.w;
    }
    unsigned short* o = msg + ((size_t)bh * nR + r) * KP + c0 + c4 * 4;
    *(ushort4*)o = make_ushort4(f2bf(acc.x), f2bf(acc.y), f2bf(acc.z), f2bf(acc.w));
  }
}

// ---------------- head fusion ---------------------------------------------------
__global__ void hfuse_k(const float* __restrict__ feats, const float* __restrict__ fw,
                        const float* __restrict__ fb, float* __restrict__ fused)
{
  size_t i = (size_t)blockIdx.x * 256 + threadIdx.x;
  constexpr size_t tot4 = (size_t)nB * nR * nT / 4;
  if (i >= tot4) return;
  size_t b = i / (nR * nT / 4);
  size_t rem = i % (nR * nT / 4);
  float fbv = fb[0];
  float4 acc = {fbv, fbv, fbv, fbv};
#pragma unroll
  for (int h = 0; h < nH; ++h) {
    float w = fw[h];
    float4 v = ((const float4*)feats)[(b * nH + h) * (nR * nT / 4) + rem];
    acc.x += w * v.x; acc.y += w * v.y; acc.z += w * v.z; acc.w += w * v.w;
  }
  ((float4*)fused)[i] = acc;
}

}  // namespace

extern "C" void kernel_launch(void* const* d_in, const int* in_sizes, int n_in,
                              void* d_out, int out_size, void* d_ws, size_t ws_size,
                              hipStream_t stream)
{
  (void)in_sizes; (void)n_in; (void)out_size; (void)ws_size;
  const float* x    = (const float*)d_in[0];
  const float* Wk   = (const float*)d_in[1];
  const float* bk   = (const float*)d_in[2];
  const float* seW1 = (const float*)d_in[3];
  const float* seb1 = (const float*)d_in[4];
  const float* seW2 = (const float*)d_in[5];
  const float* seb2 = (const float*)d_in[6];
  const float* gcnW = (const float*)d_in[7];
  const float* gcnb = (const float*)d_in[8];
  const float* fw   = (const float*)d_in[9];
  const float* fb   = (const float*)d_in[10];
  const float* mW1  = (const float*)d_in[11];
  const float* mb1  = (const float*)d_in[12];
  const float* mW2  = (const float*)d_in[13];
  const float* mb2  = (const float*)d_in[14];
  const float* mW3  = (const float*)d_in[15];
  const float* mb3  = (const float*)d_in[16];
  const float* mW4  = (const float*)d_in[17];
  const float* mb4  = (const float*)d_in[18];
  float* out = (float*)d_out;

  // workspace (float units), total ~130.6 MB:
  // [adjval 409600][adjcol 409600][gate 64][Wt 692224][feats 20480000]
  // [big 10649600 = qk (3276800) ∪ msg (10649600 as shorts) ∪ mlp bufs]
  float* ws     = (float*)d_ws;
  float* adjval = ws;
  int*   adjcol = (int*)(adjval + 409600);
  float* gate   = (float*)(adjcol + 409600);
  unsigned short* Wt = (unsigned short*)(gate + 64);          // 8*416*416 shorts
  float* feats  = gate + 64 + (size_t)8 * KP * KP / 2;        // 51200*400 f
  float* big    = feats + (size_t)51200 * 400;
  float* qk     = big;                                        // 6400*512 f
  unsigned short* msg = (unsigned short*)big;                 // 51200*416 sh
  float* fused  = big;                                        // aliases dead msg
  float* h1     = fused + (size_t)6400 * 400;
  float* h2     = h1 + (size_t)6400 * 256;
  float* h3     = h2 + (size_t)6400 * 128;

  // 0. gcn_W -> bf16, transposed (n-major), zero-padded to 416x416
  wprep_k<<<dim3(13, 13, 8), dim3(32, 8), 0, stream>>>(gcnW, Wt);

  // 1. qk = x @ Wk + bk
  gemm_k<128, 128, 16, 8, 8, false><<<dim3(4, 50), 256, 0, stream>>>(
      x, Wk, bk, qk, 6400, 512, 400);

  // 2. SE gate
  gate_k<<<1, 64, 0, stream>>>(seW1, seb1, seW2, seb2, gate);

  // 3. attention -> 7-sparse adjacency (fp32, rank-exact)
  attn_k<<<BH * 25, 256, 0, stream>>>(qk, gate, adjval, adjcol);

  // 4. 8x GCN: LDS-gather spmsg + bf16 MFMA GEMM (layer 0 sources x directly)
  for (int i = 0; i < 8; ++i) {
    spmsg_k<<<dim3(13, BH), 256, 0, stream>>>(adjcol, adjval, feats, x,
                                              (i == 0) ? 1 : 0, msg);
    gcn_gemm<<<dim3(4, 200), 256, 0, stream>>>(
        msg, Wt + (size_t)i * KP * KP, gcnb + (size_t)i * nT, feats, x,
        (i == 0) ? 1 : 0);
  }

  // 5. fuse heads
  hfuse_k<<<2500, 256, 0, stream>>>(feats, fw, fb, fused);

  // 6-9. MLP head (fp32)
  gemm_k<128, 128, 16, 8, 8, true><<<dim3(2, 50), 256, 0, stream>>>(
      fused, mW1, mb1, h1, 6400, 256, 400);
  gemm_k<64, 64, 16, 4, 4, true><<<dim3(2, 100), 256, 0, stream>>>(
      h1, mW2, mb2, h2, 6400, 128, 256);
  gemm_k<64, 64, 16, 4, 4, true><<<dim3(1, 100), 256, 0, stream>>>(
      h2, mW3, mb3, h3, 6400, 64, 128);
  gemm_k<64, 64, 16, 4, 4, true><<<dim3(1, 100), 256, 0, stream>>>(
      h3, mW4, mb4, out, 6400, 5, 64);
}

// Round 4
// 2661.983 us; speedup vs baseline: 10.9532x; 10.9532x over previous
//
#include <hip/hip_runtime.h>
#include <math.h>

namespace {

constexpr int nB = 16, nR = 400, nT = 400, nH = 8, nQ = 64;
constexpr int BH = nB * nH;   // 128
constexpr int HQ = nH * nQ;   // 512
constexpr int KP = 416;       // padded K for bf16 GCN GEMM (13 x 32)

typedef __attribute__((ext_vector_type(8))) short short8;
typedef __attribute__((ext_vector_type(4))) float floatx4;

__device__ __forceinline__ unsigned short f2bf(float f) {
  unsigned int u = __float_as_uint(f);
  unsigned int r = (u + 0x7fffu + ((u >> 16) & 1u)) >> 16;
  return (unsigned short)r;
}

__device__ __forceinline__ void gload16(const void* g, void* l) {
  __builtin_amdgcn_global_load_lds(
      (const __attribute__((address_space(1))) unsigned int*)g,
      (__attribute__((address_space(3))) unsigned int*)l, 16, 0, 0);
}

// ---------------- generic fp32 GEMM: C = act(A@W + bias) ----------------
template<int BM, int BN, int BK, int TM, int TN, bool RELU>
__global__ __launch_bounds__(256) void gemm_k(
    const float* __restrict__ A, const float* __restrict__ W,
    const float* __restrict__ bias,
    float* C, int M, int N, int K)
{
  constexpr int NT = (BM / TM) * (BN / TN);
  static_assert(NT == 256, "block must be 256 threads");
  __shared__ float As[BK][BM + 4];
  __shared__ float Bs[BK][BN + 4];
  const int tid = threadIdx.x;
  const int bm = blockIdx.y * BM;
  const int bn = blockIdx.x * BN;
  const int tx = tid % (BN / TN);
  const int ty = tid / (BN / TN);
  const bool n4ok = ((N & 3) == 0);

  float acc[TM][TN];
#pragma unroll
  for (int i = 0; i < TM; ++i)
#pragma unroll
    for (int j = 0; j < TN; ++j) acc[i][j] = 0.f;

  for (int kt = 0; kt < K; kt += BK) {
#pragma unroll
    for (int i = 0; i < (BM * BK) / (NT * 4); ++i) {
      int flat = (tid + i * NT) * 4;
      int m = flat / BK;
      int k = flat % BK;
      float4 v = *(const float4*)(A + (size_t)(bm + m) * K + kt + k);
      As[k + 0][m] = v.x; As[k + 1][m] = v.y;
      As[k + 2][m] = v.z; As[k + 3][m] = v.w;
    }
#pragma unroll
    for (int i = 0; i < (BK * BN) / (NT * 4); ++i) {
      int flat = (tid + i * NT) * 4;
      int k = flat / BN;
      int n = flat % BN;
      int gn = bn + n;
      float4 v;
      if (n4ok && gn + 3 < N) {
        v = *(const float4*)(W + (size_t)(kt + k) * N + gn);
      } else {
        v.x = (gn + 0 < N) ? W[(size_t)(kt + k) * N + gn + 0] : 0.f;
        v.y = (gn + 1 < N) ? W[(size_t)(kt + k) * N + gn + 1] : 0.f;
        v.z = (gn + 2 < N) ? W[(size_t)(kt + k) * N + gn + 2] : 0.f;
        v.w = (gn + 3 < N) ? W[(size_t)(kt + k) * N + gn + 3] : 0.f;
      }
      *(float4*)&Bs[k][n] = v;
    }
    __syncthreads();
#pragma unroll
    for (int k = 0; k < BK; ++k) {
      float a[TM], b[TN];
#pragma unroll
      for (int i = 0; i < TM; i += 4)
        *(float4*)&a[i] = *(const float4*)&As[k][ty * TM + i];
#pragma unroll
      for (int j = 0; j < TN; j += 4)
        *(float4*)&b[j] = *(const float4*)&Bs[k][tx * TN + j];
#pragma unroll
      for (int i = 0; i < TM; ++i)
#pragma unroll
        for (int j = 0; j < TN; ++j) acc[i][j] += a[i] * b[j];
    }
    __syncthreads();
  }

#pragma unroll
  for (int i = 0; i < TM; ++i) {
    const int gm = bm + ty * TM + i;
    float* crow = C + (size_t)gm * N;
#pragma unroll
    for (int j = 0; j < TN; j += 4) {
      const int gn = bn + tx * TN + j;
      if (n4ok && gn + 3 < N) {
        float4 bv = *(const float4*)(bias + gn);
        float4 v;
        v.x = acc[i][j + 0] + bv.x; v.y = acc[i][j + 1] + bv.y;
        v.z = acc[i][j + 2] + bv.z; v.w = acc[i][j + 3] + bv.w;
        if (RELU) {
          v.x = fmaxf(v.x, 0.f); v.y = fmaxf(v.y, 0.f);
          v.z = fmaxf(v.z, 0.f); v.w = fmaxf(v.w, 0.f);
        }
        *(float4*)(crow + gn) = v;
      } else {
#pragma unroll
        for (int jj = 0; jj < 4; ++jj) {
          int gnn = gn + jj;
          if (gnn < N) {
            float v = acc[i][j + jj] + bias[gnn];
            if (RELU) v = fmaxf(v, 0.f);
            crow[gnn] = v;
          }
        }
      }
    }
  }
}

// ---------------- bf16 MFMA GEMM for GCN layers (BM=256, KP=416) --------------
// A(msg): [51200][416] bf16;  Bt: [416][416] bf16 n-major;  C(feats): [51200][400]
// C = relu(A@W + bias) + (first ? broadcast(x) : C)
// NOTE: all acc loops are compile-time unrolled — dynamic indexing of acc[][]
// demotes it to scratch (HBM), the R3 regression (VGPR 48, FETCH 737 MB).
__global__ __launch_bounds__(256) void gcn_gemm(
    const unsigned short* __restrict__ A,
    const unsigned short* __restrict__ Bt,
    const float* __restrict__ bias,
    float* __restrict__ C,
    const float* __restrict__ x, int first)
{
  __shared__ __align__(128) unsigned short As[256 * 32];  // 16 KB
  __shared__ __align__(128) unsigned short Bs[128 * 32];  //  8 KB

  const int tid = threadIdx.x;
  const int lane = tid & 63;
  const int wave = tid >> 6;
  const int bm = blockIdx.y * 256;
  const int bn = blockIdx.x * 128;        // covers 512 cols; >=400 is pad
  const int wm = (wave & 1) * 128;
  const int wn = (wave >> 1) * 64;

  floatx4 acc[8][4] = {};

  // staging: A rows [wave*64, wave*64+64), B rows [wave*32, wave*32+32)
  const int lrow = lane >> 2;
  const int lk = (lane & 3) * 8;
  const unsigned short* Ag = A + (size_t)(bm + wave * 64 + lrow) * KP + lk;
  int br0 = bn + wave * 32 + lrow;      if (br0 > 415) br0 = 415;  // zero-pad row
  int br1 = bn + wave * 32 + 16 + lrow; if (br1 > 415) br1 = 415;
  const unsigned short* Bg0 = Bt + (size_t)br0 * KP + lk;
  const unsigned short* Bg1 = Bt + (size_t)br1 * KP + lk;

  const int fr = lane & 15;
  const int fkk = (lane >> 4) * 8;

  for (int kt = 0; kt < KP; kt += 32) {
#pragma unroll
    for (int i = 0; i < 4; ++i)
      gload16(Ag + (size_t)i * 16 * KP + kt, As + (wave * 4 + i) * 512);
    gload16(Bg0 + kt, Bs + (wave * 2) * 512);
    gload16(Bg1 + kt, Bs + (wave * 2 + 1) * 512);
    __syncthreads();

    short8 a[8], b[4];
#pragma unroll
    for (int mi = 0; mi < 8; ++mi)
      a[mi] = *(const short8*)(As + (wm + mi * 16 + fr) * 32 + fkk);
#pragma unroll
    for (int ni = 0; ni < 4; ++ni)
      b[ni] = *(const short8*)(Bs + (wn + ni * 16 + fr) * 32 + fkk);
#pragma unroll
    for (int mi = 0; mi < 8; ++mi)
#pragma unroll
      for (int ni = 0; ni < 4; ++ni)
        acc[mi][ni] = __builtin_amdgcn_mfma_f32_16x16x32_bf16(
            a[mi], b[ni], acc[mi][ni], 0, 0, 0);
    __syncthreads();
  }

  // epilogue: C/D layout col=lane&15, row=(lane>>4)*4+reg; guard col<400
  const int colb = bn + wn + (lane & 15);
  float bv[4];
#pragma unroll
  for (int ni = 0; ni < 4; ++ni) {
    const int col = colb + ni * 16;
    bv[ni] = (col < nT) ? bias[col] : 0.f;
  }

#pragma unroll
  for (int mi = 0; mi < 8; ++mi) {
    const int row0 = bm + wm + mi * 16 + (lane >> 4) * 4;
#pragma unroll
    for (int r = 0; r < 4; ++r) {
      const int gr = row0 + r;
      float* crow = C + (size_t)gr * nT;
      const float* resrow;
      if (first) {
        const int bh = gr / nR;
        const int rr = gr - bh * nR;
        resrow = x + (size_t)(bh >> 3) * (nR * nT) + (size_t)rr * nT;
      } else {
        resrow = crow;
      }
#pragma unroll
      for (int ni = 0; ni < 4; ++ni) {
        const int col = colb + ni * 16;
        if (col < nT)
          crow[col] = fmaxf(acc[mi][ni][r] + bv[ni], 0.f) + resrow[col];
      }
    }
  }
}

// ---------------- W prep: Wt[i][n][k] = bf16(gcn_W[i][k][n]), zero-padded ------
__global__ void wprep_k(const float* __restrict__ W, unsigned short* __restrict__ Wt)
{
  __shared__ float t[32][33];
  const int i = blockIdx.z;
  const int k0 = blockIdx.x * 32;
  const int n0 = blockIdx.y * 32;
  const int tx = threadIdx.x, ty = threadIdx.y;   // 32 x 8
#pragma unroll
  for (int r = 0; r < 32; r += 8) {
    int k = k0 + ty + r, n = n0 + tx;
    t[ty + r][tx] = (k < nT && n < nT) ? W[(size_t)i * nT * nT + (size_t)k * nT + n] : 0.f;
  }
  __syncthreads();
#pragma unroll
  for (int r = 0; r < 32; r += 8) {
    int n = n0 + ty + r, k = k0 + tx;
    Wt[(size_t)i * KP * KP + (size_t)n * KP + k] = f2bf(t[tx][ty + r]);
  }
}

// ---------------- SE gate (gap == 1/R identically) -----------------------------
__global__ void gate_k(const float* __restrict__ w1, const float* __restrict__ b1,
                       const float* __restrict__ w2, const float* __restrict__ b2,
                       float* gate)
{
  if (threadIdx.x == 0 && blockIdx.x == 0) {
    float h1[4];
    const float gap = 1.0f / 400.0f;
#pragma unroll
    for (int i = 0; i < 4; ++i) {
      float s = b1[i];
      for (int h = 0; h < 8; ++h) s += gap * w1[h * 4 + i];
      h1[i] = fmaxf(s, 0.f);
    }
#pragma unroll
    for (int h = 0; h < 8; ++h) {
      float s = b2[h];
      for (int i = 0; i < 4; ++i) s += h1[i] * w2[i * 8 + h];
      gate[h] = 1.f / (1.f + expf(-s));
    }
  }
}

// ---------------- fused scores -> relu -> softmax -> gate -> stable-rank mask --
__global__ __launch_bounds__(256) void attn_k(
    const float* __restrict__ qk, const float* __restrict__ gate,
    float* __restrict__ adjval, int* __restrict__ adjcol)
{
  __shared__ float Qs[16][68];
  __shared__ float Ks[64][68];
  __shared__ float sc[16][404];

  const int tid = threadIdx.x;
  const int blk = blockIdx.x;
  const int bh = blk / 25;
  const int rt = (blk % 25) * 16;
  const int b = bh / nH;
  const int h = bh % nH;
  const float* qkb = qk + (size_t)b * nR * HQ + h * nQ;

  {
    int r = tid >> 4;
    int q = (tid & 15) << 2;
    *(float4*)&Qs[r][q] = *(const float4*)(qkb + (size_t)(rt + r) * HQ + q);
  }

  const int r0 = (tid & 7) * 2;
  const int s0 = (tid >> 3) * 2;

  for (int st = 0; st < 7; ++st) {
    const int sn = st * 64;
    const int cnt = (nR - sn < 64) ? (nR - sn) : 64;
    __syncthreads();
#pragma unroll
    for (int i = 0; i < 4; ++i) {
      int flat = (tid + i * 256) * 4;
      int j = flat >> 6;
      int q = flat & 63;
      if (j < cnt)
        *(float4*)&Ks[j][q] = *(const float4*)(qkb + (size_t)(sn + j) * HQ + q);
    }
    __syncthreads();
    float a00 = 0.f, a01 = 0.f, a10 = 0.f, a11 = 0.f;
#pragma unroll
    for (int q4 = 0; q4 < 16; ++q4) {
      float4 qa = *(const float4*)&Qs[r0][q4 * 4];
      float4 qb = *(const float4*)&Qs[r0 + 1][q4 * 4];
      float4 ka = *(const float4*)&Ks[s0][q4 * 4];
      float4 kb = *(const float4*)&Ks[s0 + 1][q4 * 4];
      a00 += qa.x * ka.x + qa.y * ka.y + qa.z * ka.z + qa.w * ka.w;
      a01 += qa.x * kb.x + qa.y * kb.y + qa.z * kb.z + qa.w * kb.w;
      a10 += qb.x * ka.x + qb.y * ka.y + qb.z * ka.z + qb.w * ka.w;
      a11 += qb.x * kb.x + qb.y * kb.y + qb.z * kb.z + qb.w * kb.w;
    }
    if (s0 < cnt) {
      sc[r0][sn + s0]     = fmaxf(a00 * 0.125f, 0.f);
      sc[r0 + 1][sn + s0] = fmaxf(a10 * 0.125f, 0.f);
    }
    if (s0 + 1 < cnt) {
      sc[r0][sn + s0 + 1]     = fmaxf(a01 * 0.125f, 0.f);
      sc[r0 + 1][sn + s0 + 1] = fmaxf(a11 * 0.125f, 0.f);
    }
  }
  __syncthreads();

  const int tr = tid >> 4;
  const int tl = tid & 15;
  float m = 0.f;
  for (int j = tl; j < nR; j += 16) m = fmaxf(m, sc[tr][j]);
#pragma unroll
  for (int o = 8; o > 0; o >>= 1) m = fmaxf(m, __shfl_xor(m, o));
  float ssum = 0.f;
  for (int j = tl; j < nR; j += 16) {
    float e = expf(sc[tr][j] - m);
    sc[tr][j] = e;
    ssum += e;
  }
#pragma unroll
  for (int o = 8; o > 0; o >>= 1) ssum += __shfl_xor(ssum, o);
  const float g = gate[h];
  for (int j = tl; j < nR; j += 16) sc[tr][j] = (sc[tr][j] / ssum) * g;
  __syncthreads();

  const int csp[6] = {0, 16, 17, 18, 19, 20};
  float vc[6];
#pragma unroll
  for (int i = 0; i < 6; ++i) vc[i] = sc[tr][csp[i]];
  int rk[6] = {0, 0, 0, 0, 0, 0};
  for (int j = tl; j < nR; j += 16) {
    float vj = sc[tr][j];
#pragma unroll
    for (int i = 0; i < 6; ++i)
      rk[i] += (vj < vc[i]) ? 1 : ((vj == vc[i] && j < csp[i]) ? 1 : 0);
  }
#pragma unroll
  for (int i = 0; i < 6; ++i)
#pragma unroll
    for (int o = 8; o > 0; o >>= 1) rk[i] += __shfl_xor(rk[i], o);

  if (tl == 0) {
    const int rg = rt + tr;
    const size_t base = ((size_t)bh * nR + rg) * 8;
    bool dup = false;
#pragma unroll
    for (int i = 0; i < 6; ++i) {
      int p = rk[i];
      adjcol[base + i] = p;
      adjval[base + i] = sc[tr][p];
      dup = dup || (p == rg);
    }
    adjcol[base + 6] = rg;
    adjval[base + 6] = dup ? 0.f : sc[tr][rg];
    adjcol[base + 7] = rg;
    adjval[base + 7] = 0.f;
  }
}

// ---------------- sparse msg via LDS-staged feats column-chunks ----------------
__global__ __launch_bounds__(256) void spmsg_k(
    const int* __restrict__ adjcol, const float* __restrict__ adjval,
    const float* __restrict__ feats, const float* __restrict__ x, int first,
    unsigned short* __restrict__ msg)
{
  __shared__ float fs[400 * 36];   // 57.6 KB, row stride 36 floats

  const int tid = threadIdx.x;
  const int bh = blockIdx.y;
  const int c0 = blockIdx.x * 32;
  const float* src = first ? (x + (size_t)(bh >> 3) * (nR * nT))
                           : (feats + (size_t)bh * nR * nT);

  for (int i = tid; i < 3200; i += 256) {
    const int r = i >> 3, c4 = i & 7;
    const int c = c0 + c4 * 4;
    float4 v = {0.f, 0.f, 0.f, 0.f};
    if (c < 400) v = *(const float4*)(src + (size_t)r * nT + c);
    *(float4*)&fs[r * 36 + c4 * 4] = v;
  }
  __syncthreads();

  const int* ac = adjcol + (size_t)bh * nR * 8;
  const float* av = adjval + (size_t)bh * nR * 8;
  for (int i = tid; i < 3200; i += 256) {
    const int r = i >> 3, c4 = i & 7;
    float4 acc = {0.f, 0.f, 0.f, 0.f};
#pragma unroll
    for (int j = 0; j < 7; ++j) {
      const int col = ac[r * 8 + j];
      const float val = av[r * 8 + j];
      float4 v = *(const float4*)&fs[col * 36 + c4 * 4];
      acc.x += val * v.x; acc.y += val * v.y;
      acc.z += val * v.z; acc.w += val * v.w;
    }
    unsigned short* o = msg + ((size_t)bh * nR + r) * KP + c0 + c4 * 4;
    *(ushort4*)o = make_ushort4(f2bf(acc.x), f2bf(acc.y), f2bf(acc.z), f2bf(acc.w));
  }
}

// ---------------- head fusion ---------------------------------------------------
__global__ void hfuse_k(const float* __restrict__ feats, const float* __restrict__ fw,
                        const float* __restrict__ fb, float* __restrict__ fused)
{
  size_t i = (size_t)blockIdx.x * 256 + threadIdx.x;
  constexpr size_t tot4 = (size_t)nB * nR * nT / 4;
  if (i >= tot4) return;
  size_t b = i / (nR * nT / 4);
  size_t rem = i % (nR * nT / 4);
  float fbv = fb[0];
  float4 acc = {fbv, fbv, fbv, fbv};
#pragma unroll
  for (int h = 0; h < nH; ++h) {
    float w = fw[h];
    float4 v = ((const float4*)feats)[(b * nH + h) * (nR * nT / 4) + rem];
    acc.x += w * v.x; acc.y += w * v.y; acc.z += w * v.z; acc.w += w * v.w;
  }
  ((float4*)fused)[i] = acc;
}

}  // namespace

extern "C" void kernel_launch(void* const* d_in, const int* in_sizes, int n_in,
                              void* d_out, int out_size, void* d_ws, size_t ws_size,
                              hipStream_t stream)
{
  (void)in_sizes; (void)n_in; (void)out_size; (void)ws_size;
  const float* x    = (const float*)d_in[0];
  const float* Wk   = (const float*)d_in[1];
  const float* bk   = (const float*)d_in[2];
  const float* seW1 = (const float*)d_in[3];
  const float* seb1 = (const float*)d_in[4];
  const float* seW2 = (const float*)d_in[5];
  const float* seb2 = (const float*)d_in[6];
  const float* gcnW = (const float*)d_in[7];
  const float* gcnb = (const float*)d_in[8];
  const float* fw   = (const float*)d_in[9];
  const float* fb   = (const float*)d_in[10];
  const float* mW1  = (const float*)d_in[11];
  const float* mb1  = (const float*)d_in[12];
  const float* mW2  = (const float*)d_in[13];
  const float* mb2  = (const float*)d_in[14];
  const float* mW3  = (const float*)d_in[15];
  const float* mb3  = (const float*)d_in[16];
  const float* mW4  = (const float*)d_in[17];
  const float* mb4  = (const float*)d_in[18];
  float* out = (float*)d_out;

  // workspace (float units), total ~130.6 MB
  float* ws     = (float*)d_ws;
  float* adjval = ws;
  int*   adjcol = (int*)(adjval + 409600);
  float* gate   = (float*)(adjcol + 409600);
  unsigned short* Wt = (unsigned short*)(gate + 64);          // 8*416*416 shorts
  float* feats  = gate + 64 + (size_t)8 * KP * KP / 2;        // 51200*400 f
  float* big    = feats + (size_t)51200 * 400;
  float* qk     = big;                                        // 6400*512 f
  unsigned short* msg = (unsigned short*)big;                 // 51200*416 sh
  float* fused  = big;                                        // aliases dead msg
  float* h1     = fused + (size_t)6400 * 400;
  float* h2     = h1 + (size_t)6400 * 256;
  float* h3     = h2 + (size_t)6400 * 128;

  // 0. gcn_W -> bf16, transposed (n-major), zero-padded to 416x416
  wprep_k<<<dim3(13, 13, 8), dim3(32, 8), 0, stream>>>(gcnW, Wt);

  // 1. qk = x @ Wk + bk
  gemm_k<128, 128, 16, 8, 8, false><<<dim3(4, 50), 256, 0, stream>>>(
      x, Wk, bk, qk, 6400, 512, 400);

  // 2. SE gate
  gate_k<<<1, 64, 0, stream>>>(seW1, seb1, seW2, seb2, gate);

  // 3. attention -> 7-sparse adjacency (fp32, rank-exact)
  attn_k<<<BH * 25, 256, 0, stream>>>(qk, gate, adjval, adjcol);

  // 4. 8x GCN: LDS-gather spmsg + bf16 MFMA GEMM (layer 0 sources x directly)
  for (int i = 0; i < 8; ++i) {
    spmsg_k<<<dim3(13, BH), 256, 0, stream>>>(adjcol, adjval, feats, x,
                                              (i == 0) ? 1 : 0, msg);
    gcn_gemm<<<dim3(4, 200), 256, 0, stream>>>(
        msg, Wt + (size_t)i * KP * KP, gcnb + (size_t)i * nT, feats, x,
        (i == 0) ? 1 : 0);
  }

  // 5. fuse heads
  hfuse_k<<<2500, 256, 0, stream>>>(feats, fw, fb, fused);

  // 6-9. MLP head (fp32)
  gemm_k<128, 128, 16, 8, 8, true><<<dim3(2, 50), 256, 0, stream>>>(
      fused, mW1, mb1, h1, 6400, 256, 400);
  gemm_k<64, 64, 16, 4, 4, true><<<dim3(2, 100), 256, 0, stream>>>(
      h1, mW2, mb2, h2, 6400, 128, 256);
  gemm_k<64, 64, 16, 4, 4, true><<<dim3(1, 100), 256, 0, stream>>>(
      h2, mW3, mb3, h3, 6400, 64, 128);
  gemm_k<64, 64, 16, 4, 4, true><<<dim3(1, 100), 256, 0, stream>>>(
      h3, mW4, mb4, out, 6400, 5, 64);
}

// Round 5
// 1818.724 us; speedup vs baseline: 16.0317x; 1.4637x over previous
//
#include <hip/hip_runtime.h>
#include <math.h>

namespace {

constexpr int nB = 16, nR = 400, nT = 400, nH = 8, nQ = 64;
constexpr int BH = nB * nH;   // 128
constexpr int HQ = nH * nQ;   // 512
constexpr int KP = 416;       // padded K for bf16 GCN GEMM (13 x 32)

typedef __attribute__((ext_vector_type(8))) short short8;
typedef __attribute__((ext_vector_type(4))) float floatx4;

__device__ __forceinline__ unsigned short f2bf(float f) {
  unsigned int u = __float_as_uint(f);
  unsigned int r = (u + 0x7fffu + ((u >> 16) & 1u)) >> 16;
  return (unsigned short)r;
}

__device__ __forceinline__ void gload16(const void* g, void* l) {
  __builtin_amdgcn_global_load_lds(
      (const __attribute__((address_space(1))) unsigned int*)g,
      (__attribute__((address_space(3))) unsigned int*)l, 16, 0, 0);
}

// ---------------- generic fp32 GEMM: C = act(A@W + bias) ----------------
template<int BM, int BN, int BK, int TM, int TN, bool RELU>
__global__ __launch_bounds__(256) void gemm_k(
    const float* __restrict__ A, const float* __restrict__ W,
    const float* __restrict__ bias,
    float* C, int M, int N, int K)
{
  constexpr int NT = (BM / TM) * (BN / TN);
  static_assert(NT == 256, "block must be 256 threads");
  __shared__ float As[BK][BM + 4];
  __shared__ float Bs[BK][BN + 4];
  const int tid = threadIdx.x;
  const int bm = blockIdx.y * BM;
  const int bn = blockIdx.x * BN;
  const int tx = tid % (BN / TN);
  const int ty = tid / (BN / TN);
  const bool n4ok = ((N & 3) == 0);

  float acc[TM][TN];
#pragma unroll
  for (int i = 0; i < TM; ++i)
#pragma unroll
    for (int j = 0; j < TN; ++j) acc[i][j] = 0.f;

  for (int kt = 0; kt < K; kt += BK) {
#pragma unroll
    for (int i = 0; i < (BM * BK) / (NT * 4); ++i) {
      int flat = (tid + i * NT) * 4;
      int m = flat / BK;
      int k = flat % BK;
      float4 v = *(const float4*)(A + (size_t)(bm + m) * K + kt + k);
      As[k + 0][m] = v.x; As[k + 1][m] = v.y;
      As[k + 2][m] = v.z; As[k + 3][m] = v.w;
    }
#pragma unroll
    for (int i = 0; i < (BK * BN) / (NT * 4); ++i) {
      int flat = (tid + i * NT) * 4;
      int k = flat / BN;
      int n = flat % BN;
      int gn = bn + n;
      float4 v;
      if (n4ok && gn + 3 < N) {
        v = *(const float4*)(W + (size_t)(kt + k) * N + gn);
      } else {
        v.x = (gn + 0 < N) ? W[(size_t)(kt + k) * N + gn + 0] : 0.f;
        v.y = (gn + 1 < N) ? W[(size_t)(kt + k) * N + gn + 1] : 0.f;
        v.z = (gn + 2 < N) ? W[(size_t)(kt + k) * N + gn + 2] : 0.f;
        v.w = (gn + 3 < N) ? W[(size_t)(kt + k) * N + gn + 3] : 0.f;
      }
      *(float4*)&Bs[k][n] = v;
    }
    __syncthreads();
#pragma unroll
    for (int k = 0; k < BK; ++k) {
      float a[TM], b[TN];
#pragma unroll
      for (int i = 0; i < TM; i += 4)
        *(float4*)&a[i] = *(const float4*)&As[k][ty * TM + i];
#pragma unroll
      for (int j = 0; j < TN; j += 4)
        *(float4*)&b[j] = *(const float4*)&Bs[k][tx * TN + j];
#pragma unroll
      for (int i = 0; i < TM; ++i)
#pragma unroll
        for (int j = 0; j < TN; ++j) acc[i][j] += a[i] * b[j];
    }
    __syncthreads();
  }

#pragma unroll
  for (int i = 0; i < TM; ++i) {
    const int gm = bm + ty * TM + i;
    float* crow = C + (size_t)gm * N;
#pragma unroll
    for (int j = 0; j < TN; j += 4) {
      const int gn = bn + tx * TN + j;
      if (n4ok && gn + 3 < N) {
        float4 bv = *(const float4*)(bias + gn);
        float4 v;
        v.x = acc[i][j + 0] + bv.x; v.y = acc[i][j + 1] + bv.y;
        v.z = acc[i][j + 2] + bv.z; v.w = acc[i][j + 3] + bv.w;
        if (RELU) {
          v.x = fmaxf(v.x, 0.f); v.y = fmaxf(v.y, 0.f);
          v.z = fmaxf(v.z, 0.f); v.w = fmaxf(v.w, 0.f);
        }
        *(float4*)(crow + gn) = v;
      } else {
#pragma unroll
        for (int jj = 0; jj < 4; ++jj) {
          int gnn = gn + jj;
          if (gnn < N) {
            float v = acc[i][j + jj] + bias[gnn];
            if (RELU) v = fmaxf(v, 0.f);
            crow[gnn] = v;
          }
        }
      }
    }
  }
}

// ---------------- bf16 MFMA GEMM for GCN layers (128x128 tile, KP=416) --------
// m97 shape: 4 waves, each 64x64 via 4x4 of 16x16x32 -> 64 AGPR acc, ~3 w/SIMD.
// (R4's BM=256 / acc[8][4] crossed the 256-reg occupancy cliff: 1 wave/SIMD,
//  Occupancy 3.2%, 225 us/layer. Do not enlarge the accumulator tile.)
// A(msg): [51200][416] bf16;  Bt: [416][416] bf16 n-major;  C(feats): [51200][400]
// C = relu(A@W + bias) + (first ? broadcast(x) : C)
__global__ __launch_bounds__(256) void gcn_gemm(
    const unsigned short* __restrict__ A,
    const unsigned short* __restrict__ Bt,
    const float* __restrict__ bias,
    float* __restrict__ C,
    const float* __restrict__ x, int first)
{
  __shared__ __align__(128) unsigned short As[128 * 32];  // 8 KB
  __shared__ __align__(128) unsigned short Bs[128 * 32];  // 8 KB

  const int tid = threadIdx.x;
  const int lane = tid & 63;
  const int wave = tid >> 6;
  const int bm = blockIdx.y * 128;
  const int bn = blockIdx.x * 128;        // covers 512 cols; >=400 is pad
  const int wm = (wave & 1) * 64;
  const int wn = (wave >> 1) * 64;

  floatx4 acc[4][4] = {};

  // staging: each wave stages 2 A-chunks + 2 B-chunks (16 rows x 32 k each)
  const int r0 = wave * 32 + (lane >> 2);
  const int c0 = (lane & 3) * 8;
  const unsigned short* Ag0 = A + (size_t)(bm + r0) * KP + c0;
  const unsigned short* Ag1 = A + (size_t)(bm + r0 + 16) * KP + c0;
  int br0 = bn + r0;      if (br0 > 415) br0 = 415;  // zero-pad row of Wt
  int br1 = bn + r0 + 16; if (br1 > 415) br1 = 415;
  const unsigned short* Bg0 = Bt + (size_t)br0 * KP + c0;
  const unsigned short* Bg1 = Bt + (size_t)br1 * KP + c0;
  unsigned short* Al0 = As + (wave * 2) * 512;
  unsigned short* Al1 = As + (wave * 2 + 1) * 512;
  unsigned short* Bl0 = Bs + (wave * 2) * 512;
  unsigned short* Bl1 = Bs + (wave * 2 + 1) * 512;

  const int fr = lane & 15;
  const int fkk = (lane >> 4) * 8;

  for (int kt = 0; kt < KP; kt += 32) {
    gload16(Ag0 + kt, Al0);
    gload16(Ag1 + kt, Al1);
    gload16(Bg0 + kt, Bl0);
    gload16(Bg1 + kt, Bl1);
    __syncthreads();

    short8 a[4], b[4];
#pragma unroll
    for (int mi = 0; mi < 4; ++mi)
      a[mi] = *(const short8*)(As + (wm + mi * 16 + fr) * 32 + fkk);
#pragma unroll
    for (int ni = 0; ni < 4; ++ni)
      b[ni] = *(const short8*)(Bs + (wn + ni * 16 + fr) * 32 + fkk);
#pragma unroll
    for (int mi = 0; mi < 4; ++mi)
#pragma unroll
      for (int ni = 0; ni < 4; ++ni)
        acc[mi][ni] = __builtin_amdgcn_mfma_f32_16x16x32_bf16(
            a[mi], b[ni], acc[mi][ni], 0, 0, 0);
    __syncthreads();
  }

  // epilogue: C/D layout col=lane&15, row=(lane>>4)*4+reg; guard col<400
  const int colb = bn + wn + (lane & 15);
  float bv[4];
#pragma unroll
  for (int ni = 0; ni < 4; ++ni) {
    const int col = colb + ni * 16;
    bv[ni] = (col < nT) ? bias[col] : 0.f;
  }

#pragma unroll
  for (int mi = 0; mi < 4; ++mi) {
    const int row0 = bm + wm + mi * 16 + (lane >> 4) * 4;
#pragma unroll
    for (int r = 0; r < 4; ++r) {
      const int gr = row0 + r;
      float* crow = C + (size_t)gr * nT;
      const float* resrow;
      if (first) {
        const int bh = gr / nR;
        const int rr = gr - bh * nR;
        resrow = x + (size_t)(bh >> 3) * (nR * nT) + (size_t)rr * nT;
      } else {
        resrow = crow;
      }
#pragma unroll
      for (int ni = 0; ni < 4; ++ni) {
        const int col = colb + ni * 16;
        if (col < nT)
          crow[col] = fmaxf(acc[mi][ni][r] + bv[ni], 0.f) + resrow[col];
      }
    }
  }
}

// ---------------- W prep: Wt[i][n][k] = bf16(gcn_W[i][k][n]), zero-padded ------
__global__ void wprep_k(const float* __restrict__ W, unsigned short* __restrict__ Wt)
{
  __shared__ float t[32][33];
  const int i = blockIdx.z;
  const int k0 = blockIdx.x * 32;
  const int n0 = blockIdx.y * 32;
  const int tx = threadIdx.x, ty = threadIdx.y;   // 32 x 8
#pragma unroll
  for (int r = 0; r < 32; r += 8) {
    int k = k0 + ty + r, n = n0 + tx;
    t[ty + r][tx] = (k < nT && n < nT) ? W[(size_t)i * nT * nT + (size_t)k * nT + n] : 0.f;
  }
  __syncthreads();
#pragma unroll
  for (int r = 0; r < 32; r += 8) {
    int n = n0 + ty + r, k = k0 + tx;
    Wt[(size_t)i * KP * KP + (size_t)n * KP + k] = f2bf(t[tx][ty + r]);
  }
}

// ---------------- SE gate (gap == 1/R identically) -----------------------------
__global__ void gate_k(const float* __restrict__ w1, const float* __restrict__ b1,
                       const float* __restrict__ w2, const float* __restrict__ b2,
                       float* gate)
{
  if (threadIdx.x == 0 && blockIdx.x == 0) {
    float h1[4];
    const float gap = 1.0f / 400.0f;
#pragma unroll
    for (int i = 0; i < 4; ++i) {
      float s = b1[i];
      for (int h = 0; h < 8; ++h) s += gap * w1[h * 4 + i];
      h1[i] = fmaxf(s, 0.f);
    }
#pragma unroll
    for (int h = 0; h < 8; ++h) {
      float s = b2[h];
      for (int i = 0; i < 4; ++i) s += h1[i] * w2[i * 8 + h];
      gate[h] = 1.f / (1.f + expf(-s));
    }
  }
}

// ---------------- fused scores -> relu -> softmax -> gate -> stable-rank mask --
__global__ __launch_bounds__(256) void attn_k(
    const float* __restrict__ qk, const float* __restrict__ gate,
    float* __restrict__ adjval, int* __restrict__ adjcol)
{
  __shared__ float Qs[16][68];
  __shared__ float Ks[64][68];
  __shared__ float sc[16][404];

  const int tid = threadIdx.x;
  const int blk = blockIdx.x;
  const int bh = blk / 25;
  const int rt = (blk % 25) * 16;
  const int b = bh / nH;
  const int h = bh % nH;
  const float* qkb = qk + (size_t)b * nR * HQ + h * nQ;

  {
    int r = tid >> 4;
    int q = (tid & 15) << 2;
    *(float4*)&Qs[r][q] = *(const float4*)(qkb + (size_t)(rt + r) * HQ + q);
  }

  const int r0 = (tid & 7) * 2;
  const int s0 = (tid >> 3) * 2;

  for (int st = 0; st < 7; ++st) {
    const int sn = st * 64;
    const int cnt = (nR - sn < 64) ? (nR - sn) : 64;
    __syncthreads();
#pragma unroll
    for (int i = 0; i < 4; ++i) {
      int flat = (tid + i * 256) * 4;
      int j = flat >> 6;
      int q = flat & 63;
      if (j < cnt)
        *(float4*)&Ks[j][q] = *(const float4*)(qkb + (size_t)(sn + j) * HQ + q);
    }
    __syncthreads();
    float a00 = 0.f, a01 = 0.f, a10 = 0.f, a11 = 0.f;
#pragma unroll
    for (int q4 = 0; q4 < 16; ++q4) {
      float4 qa = *(const float4*)&Qs[r0][q4 * 4];
      float4 qb = *(const float4*)&Qs[r0 + 1][q4 * 4];
      float4 ka = *(const float4*)&Ks[s0][q4 * 4];
      float4 kb = *(const float4*)&Ks[s0 + 1][q4 * 4];
      a00 += qa.x * ka.x + qa.y * ka.y + qa.z * ka.z + qa.w * ka.w;
      a01 += qa.x * kb.x + qa.y * kb.y + qa.z * kb.z + qa.w * kb.w;
      a10 += qb.x * ka.x + qb.y * ka.y + qb.z * ka.z + qb.w * ka.w;
      a11 += qb.x * kb.x + qb.y * kb.y + qb.z * kb.z + qb.w * kb.w;
    }
    if (s0 < cnt) {
      sc[r0][sn + s0]     = fmaxf(a00 * 0.125f, 0.f);
      sc[r0 + 1][sn + s0] = fmaxf(a10 * 0.125f, 0.f);
    }
    if (s0 + 1 < cnt) {
      sc[r0][sn + s0 + 1]     = fmaxf(a01 * 0.125f, 0.f);
      sc[r0 + 1][sn + s0 + 1] = fmaxf(a11 * 0.125f, 0.f);
    }
  }
  __syncthreads();

  const int tr = tid >> 4;
  const int tl = tid & 15;
  float m = 0.f;
  for (int j = tl; j < nR; j += 16) m = fmaxf(m, sc[tr][j]);
#pragma unroll
  for (int o = 8; o > 0; o >>= 1) m = fmaxf(m, __shfl_xor(m, o));
  float ssum = 0.f;
  for (int j = tl; j < nR; j += 16) {
    float e = expf(sc[tr][j] - m);
    sc[tr][j] = e;
    ssum += e;
  }
#pragma unroll
  for (int o = 8; o > 0; o >>= 1) ssum += __shfl_xor(ssum, o);
  const float g = gate[h];
  for (int j = tl; j < nR; j += 16) sc[tr][j] = (sc[tr][j] / ssum) * g;
  __syncthreads();

  const int csp[6] = {0, 16, 17, 18, 19, 20};
  float vc[6];
#pragma unroll
  for (int i = 0; i < 6; ++i) vc[i] = sc[tr][csp[i]];
  int rk[6] = {0, 0, 0, 0, 0, 0};
  for (int j = tl; j < nR; j += 16) {
    float vj = sc[tr][j];
#pragma unroll
    for (int i = 0; i < 6; ++i)
      rk[i] += (vj < vc[i]) ? 1 : ((vj == vc[i] && j < csp[i]) ? 1 : 0);
  }
#pragma unroll
  for (int i = 0; i < 6; ++i)
#pragma unroll
    for (int o = 8; o > 0; o >>= 1) rk[i] += __shfl_xor(rk[i], o);

  if (tl == 0) {
    const int rg = rt + tr;
    const size_t base = ((size_t)bh * nR + rg) * 8;
    bool dup = false;
#pragma unroll
    for (int i = 0; i < 6; ++i) {
      int p = rk[i];
      adjcol[base + i] = p;
      adjval[base + i] = sc[tr][p];
      dup = dup || (p == rg);
    }
    adjcol[base + 6] = rg;
    adjval[base + 6] = dup ? 0.f : sc[tr][rg];
    adjcol[base + 7] = rg;
    adjval[base + 7] = 0.f;
  }
}

// ---------------- sparse msg via LDS-staged feats column-chunks ----------------
__global__ __launch_bounds__(256) void spmsg_k(
    const int* __restrict__ adjcol, const float* __restrict__ adjval,
    const float* __restrict__ feats, const float* __restrict__ x, int first,
    unsigned short* __restrict__ msg)
{
  __shared__ float fs[400 * 36];   // 57.6 KB, row stride 36 floats

  const int tid = threadIdx.x;
  const int bh = blockIdx.y;
  const int c0 = blockIdx.x * 32;
  const float* src = first ? (x + (size_t)(bh >> 3) * (nR * nT))
                           : (feats + (size_t)bh * nR * nT);

  for (int i = tid; i < 3200; i += 256) {
    const int r = i >> 3, c4 = i & 7;
    const int c = c0 + c4 * 4;
    float4 v = {0.f, 0.f, 0.f, 0.f};
    if (c < 400) v = *(const float4*)(src + (size_t)r * nT + c);
    *(float4*)&fs[r * 36 + c4 * 4] = v;
  }
  __syncthreads();

  const int* ac = adjcol + (size_t)bh * nR * 8;
  const float* av = adjval + (size_t)bh * nR * 8;
  for (int i = tid; i < 3200; i += 256) {
    const int r = i >> 3, c4 = i & 7;
    float4 acc = {0.f, 0.f, 0.f, 0.f};
#pragma unroll
    for (int j = 0; j < 7; ++j) {
      const int col = ac[r * 8 + j];
      const float val = av[r * 8 + j];
      float4 v = *(const float4*)&fs[col * 36 + c4 * 4];
      acc.x += val * v.x; acc.y += val * v.y;
      acc.z += val * v.z; acc.w += val * v.w;
    }
    unsigned short* o = msg + ((size_t)bh * nR + r) * KP + c0 + c4 * 4;
    *(ushort4*)o = make_ushort4(f2bf(acc.x), f2bf(acc.y), f2bf(acc.z), f2bf(acc.w));
  }
}

// ---------------- head fusion ---------------------------------------------------
__global__ void hfuse_k(const float* __restrict__ feats, const float* __restrict__ fw,
                        const float* __restrict__ fb, float* __restrict__ fused)
{
  size_t i = (size_t)blockIdx.x * 256 + threadIdx.x;
  constexpr size_t tot4 = (size_t)nB * nR * nT / 4;
  if (i >= tot4) return;
  size_t b = i / (nR * nT / 4);
  size_t rem = i % (nR * nT / 4);
  float fbv = fb[0];
  float4 acc = {fbv, fbv, fbv, fbv};
#pragma unroll
  for (int h = 0; h < nH; ++h) {
    float w = fw[h];
    float4 v = ((const float4*)feats)[(b * nH + h) * (nR * nT / 4) + rem];
    acc.x += w * v.x; acc.y += w * v.y; acc.z += w * v.z; acc.w += w * v.w;
  }
  ((float4*)fused)[i] = acc;
}

}  // namespace

extern "C" void kernel_launch(void* const* d_in, const int* in_sizes, int n_in,
                              void* d_out, int out_size, void* d_ws, size_t ws_size,
                              hipStream_t stream)
{
  (void)in_sizes; (void)n_in; (void)out_size; (void)ws_size;
  const float* x    = (const float*)d_in[0];
  const float* Wk   = (const float*)d_in[1];
  const float* bk   = (const float*)d_in[2];
  const float* seW1 = (const float*)d_in[3];
  const float* seb1 = (const float*)d_in[4];
  const float* seW2 = (const float*)d_in[5];
  const float* seb2 = (const float*)d_in[6];
  const float* gcnW = (const float*)d_in[7];
  const float* gcnb = (const float*)d_in[8];
  const float* fw   = (const float*)d_in[9];
  const float* fb   = (const float*)d_in[10];
  const float* mW1  = (const float*)d_in[11];
  const float* mb1  = (const float*)d_in[12];
  const float* mW2  = (const float*)d_in[13];
  const float* mb2  = (const float*)d_in[14];
  const float* mW3  = (const float*)d_in[15];
  const float* mb3  = (const float*)d_in[16];
  const float* mW4  = (const float*)d_in[17];
  const float* mb4  = (const float*)d_in[18];
  float* out = (float*)d_out;

  // workspace (float units), total ~130.6 MB
  float* ws     = (float*)d_ws;
  float* adjval = ws;
  int*   adjcol = (int*)(adjval + 409600);
  float* gate   = (float*)(adjcol + 409600);
  unsigned short* Wt = (unsigned short*)(gate + 64);          // 8*416*416 shorts
  float* feats  = gate + 64 + (size_t)8 * KP * KP / 2;        // 51200*400 f
  float* big    = feats + (size_t)51200 * 400;
  float* qk     = big;                                        // 6400*512 f
  unsigned short* msg = (unsigned short*)big;                 // 51200*416 sh
  float* fused  = big;                                        // aliases dead msg
  float* h1     = fused + (size_t)6400 * 400;
  float* h2     = h1 + (size_t)6400 * 256;
  float* h3     = h2 + (size_t)6400 * 128;

  // 0. gcn_W -> bf16, transposed (n-major), zero-padded to 416x416
  wprep_k<<<dim3(13, 13, 8), dim3(32, 8), 0, stream>>>(gcnW, Wt);

  // 1. qk = x @ Wk + bk
  gemm_k<128, 128, 16, 8, 8, false><<<dim3(4, 50), 256, 0, stream>>>(
      x, Wk, bk, qk, 6400, 512, 400);

  // 2. SE gate
  gate_k<<<1, 64, 0, stream>>>(seW1, seb1, seW2, seb2, gate);

  // 3. attention -> 7-sparse adjacency (fp32, rank-exact)
  attn_k<<<BH * 25, 256, 0, stream>>>(qk, gate, adjval, adjcol);

  // 4. 8x GCN: LDS-gather spmsg + bf16 MFMA GEMM (layer 0 sources x directly)
  for (int i = 0; i < 8; ++i) {
    spmsg_k<<<dim3(13, BH), 256, 0, stream>>>(adjcol, adjval, feats, x,
                                              (i == 0) ? 1 : 0, msg);
    gcn_gemm<<<dim3(4, 400), 256, 0, stream>>>(
        msg, Wt + (size_t)i * KP * KP, gcnb + (size_t)i * nT, feats, x,
        (i == 0) ? 1 : 0);
  }

  // 5. fuse heads
  hfuse_k<<<2500, 256, 0, stream>>>(feats, fw, fb, fused);

  // 6-9. MLP head (fp32)
  gemm_k<128, 128, 16, 8, 8, true><<<dim3(2, 50), 256, 0, stream>>>(
      fused, mW1, mb1, h1, 6400, 256, 400);
  gemm_k<64, 64, 16, 4, 4, true><<<dim3(2, 100), 256, 0, stream>>>(
      h1, mW2, mb2, h2, 6400, 128, 256);
  gemm_k<64, 64, 16, 4, 4, true><<<dim3(1, 100), 256, 0, stream>>>(
      h2, mW3, mb3, h3, 6400, 64, 128);
  gemm_k<64, 64, 16, 4, 4, true><<<dim3(1, 100), 256, 0, stream>>>(
      h3, mW4, mb4, out, 6400, 5, 64);
}

// Round 6
// 1759.680 us; speedup vs baseline: 16.5697x; 1.0336x over previous
//
#include <hip/hip_runtime.h>
#include <math.h>

namespace {

constexpr int nB = 16, nR = 400, nT = 400, nH = 8, nQ = 64;
constexpr int BH = nB * nH;   // 128
constexpr int HQ = nH * nQ;   // 512
constexpr int KP = 416;       // padded K for bf16 GCN GEMM (13 x 32)

typedef __attribute__((ext_vector_type(8))) short short8;
typedef __attribute__((ext_vector_type(4))) float floatx4;

__device__ __forceinline__ unsigned short f2bf(float f) {
  unsigned int u = __float_as_uint(f);
  unsigned int r = (u + 0x7fffu + ((u >> 16) & 1u)) >> 16;
  return (unsigned short)r;
}

__device__ __forceinline__ void gload16(const void* g, void* l) {
  __builtin_amdgcn_global_load_lds(
      (const __attribute__((address_space(1))) unsigned int*)g,
      (__attribute__((address_space(3))) unsigned int*)l, 16, 0, 0);
}

// ---------------- generic fp32 GEMM: C = act(A@W + bias) ----------------
template<int BM, int BN, int BK, int TM, int TN, bool RELU>
__global__ __launch_bounds__(256) void gemm_k(
    const float* __restrict__ A, const float* __restrict__ W,
    const float* __restrict__ bias,
    float* C, int M, int N, int K)
{
  constexpr int NT = (BM / TM) * (BN / TN);
  static_assert(NT == 256, "block must be 256 threads");
  __shared__ float As[BK][BM + 4];
  __shared__ float Bs[BK][BN + 4];
  const int tid = threadIdx.x;
  const int bm = blockIdx.y * BM;
  const int bn = blockIdx.x * BN;
  const int tx = tid % (BN / TN);
  const int ty = tid / (BN / TN);
  const bool n4ok = ((N & 3) == 0);

  float acc[TM][TN];
#pragma unroll
  for (int i = 0; i < TM; ++i)
#pragma unroll
    for (int j = 0; j < TN; ++j) acc[i][j] = 0.f;

  for (int kt = 0; kt < K; kt += BK) {
#pragma unroll
    for (int i = 0; i < (BM * BK) / (NT * 4); ++i) {
      int flat = (tid + i * NT) * 4;
      int m = flat / BK;
      int k = flat % BK;
      float4 v = *(const float4*)(A + (size_t)(bm + m) * K + kt + k);
      As[k + 0][m] = v.x; As[k + 1][m] = v.y;
      As[k + 2][m] = v.z; As[k + 3][m] = v.w;
    }
#pragma unroll
    for (int i = 0; i < (BK * BN) / (NT * 4); ++i) {
      int flat = (tid + i * NT) * 4;
      int k = flat / BN;
      int n = flat % BN;
      int gn = bn + n;
      float4 v;
      if (n4ok && gn + 3 < N) {
        v = *(const float4*)(W + (size_t)(kt + k) * N + gn);
      } else {
        v.x = (gn + 0 < N) ? W[(size_t)(kt + k) * N + gn + 0] : 0.f;
        v.y = (gn + 1 < N) ? W[(size_t)(kt + k) * N + gn + 1] : 0.f;
        v.z = (gn + 2 < N) ? W[(size_t)(kt + k) * N + gn + 2] : 0.f;
        v.w = (gn + 3 < N) ? W[(size_t)(kt + k) * N + gn + 3] : 0.f;
      }
      *(float4*)&Bs[k][n] = v;
    }
    __syncthreads();
#pragma unroll
    for (int k = 0; k < BK; ++k) {
      float a[TM], b[TN];
#pragma unroll
      for (int i = 0; i < TM; i += 4)
        *(float4*)&a[i] = *(const float4*)&As[k][ty * TM + i];
#pragma unroll
      for (int j = 0; j < TN; j += 4)
        *(float4*)&b[j] = *(const float4*)&Bs[k][tx * TN + j];
#pragma unroll
      for (int i = 0; i < TM; ++i)
#pragma unroll
        for (int j = 0; j < TN; ++j) acc[i][j] += a[i] * b[j];
    }
    __syncthreads();
  }

#pragma unroll
  for (int i = 0; i < TM; ++i) {
    const int gm = bm + ty * TM + i;
    float* crow = C + (size_t)gm * N;
#pragma unroll
    for (int j = 0; j < TN; j += 4) {
      const int gn = bn + tx * TN + j;
      if (n4ok && gn + 3 < N) {
        float4 bv = *(const float4*)(bias + gn);
        float4 v;
        v.x = acc[i][j + 0] + bv.x; v.y = acc[i][j + 1] + bv.y;
        v.z = acc[i][j + 2] + bv.z; v.w = acc[i][j + 3] + bv.w;
        if (RELU) {
          v.x = fmaxf(v.x, 0.f); v.y = fmaxf(v.y, 0.f);
          v.z = fmaxf(v.z, 0.f); v.w = fmaxf(v.w, 0.f);
        }
        *(float4*)(crow + gn) = v;
      } else {
#pragma unroll
        for (int jj = 0; jj < 4; ++jj) {
          int gnn = gn + jj;
          if (gnn < N) {
            float v = acc[i][j + jj] + bias[gnn];
            if (RELU) v = fmaxf(v, 0.f);
            crow[gnn] = v;
          }
        }
      }
    }
  }
}

// ---------------- bf16 MFMA GEMM for GCN layers (128x128 tile, KP=416) --------
__global__ __launch_bounds__(256) void gcn_gemm(
    const unsigned short* __restrict__ A,
    const unsigned short* __restrict__ Bt,
    const float* __restrict__ bias,
    float* __restrict__ C,
    const float* __restrict__ x, int first)
{
  __shared__ __align__(128) unsigned short As[128 * 32];  // 8 KB
  __shared__ __align__(128) unsigned short Bs[128 * 32];  // 8 KB

  const int tid = threadIdx.x;
  const int lane = tid & 63;
  const int wave = tid >> 6;
  const int bm = blockIdx.y * 128;
  const int bn = blockIdx.x * 128;        // covers 512 cols; >=400 is pad
  const int wm = (wave & 1) * 64;
  const int wn = (wave >> 1) * 64;

  floatx4 acc[4][4] = {};

  const int r0 = wave * 32 + (lane >> 2);
  const int c0 = (lane & 3) * 8;
  const unsigned short* Ag0 = A + (size_t)(bm + r0) * KP + c0;
  const unsigned short* Ag1 = A + (size_t)(bm + r0 + 16) * KP + c0;
  int br0 = bn + r0;      if (br0 > 415) br0 = 415;  // zero-pad row of Wt
  int br1 = bn + r0 + 16; if (br1 > 415) br1 = 415;
  const unsigned short* Bg0 = Bt + (size_t)br0 * KP + c0;
  const unsigned short* Bg1 = Bt + (size_t)br1 * KP + c0;
  unsigned short* Al0 = As + (wave * 2) * 512;
  unsigned short* Al1 = As + (wave * 2 + 1) * 512;
  unsigned short* Bl0 = Bs + (wave * 2) * 512;
  unsigned short* Bl1 = Bs + (wave * 2 + 1) * 512;

  const int fr = lane & 15;
  const int fkk = (lane >> 4) * 8;

  for (int kt = 0; kt < KP; kt += 32) {
    gload16(Ag0 + kt, Al0);
    gload16(Ag1 + kt, Al1);
    gload16(Bg0 + kt, Bl0);
    gload16(Bg1 + kt, Bl1);
    __syncthreads();

    short8 a[4], b[4];
#pragma unroll
    for (int mi = 0; mi < 4; ++mi)
      a[mi] = *(const short8*)(As + (wm + mi * 16 + fr) * 32 + fkk);
#pragma unroll
    for (int ni = 0; ni < 4; ++ni)
      b[ni] = *(const short8*)(Bs + (wn + ni * 16 + fr) * 32 + fkk);
#pragma unroll
    for (int mi = 0; mi < 4; ++mi)
#pragma unroll
      for (int ni = 0; ni < 4; ++ni)
        acc[mi][ni] = __builtin_amdgcn_mfma_f32_16x16x32_bf16(
            a[mi], b[ni], acc[mi][ni], 0, 0, 0);
    __syncthreads();
  }

  const int colb = bn + wn + (lane & 15);
  float bv[4];
#pragma unroll
  for (int ni = 0; ni < 4; ++ni) {
    const int col = colb + ni * 16;
    bv[ni] = (col < nT) ? bias[col] : 0.f;
  }

#pragma unroll
  for (int mi = 0; mi < 4; ++mi) {
    const int row0 = bm + wm + mi * 16 + (lane >> 4) * 4;
#pragma unroll
    for (int r = 0; r < 4; ++r) {
      const int gr = row0 + r;
      float* crow = C + (size_t)gr * nT;
      const float* resrow;
      if (first) {
        const int bh = gr / nR;
        const int rr = gr - bh * nR;
        resrow = x + (size_t)(bh >> 3) * (nR * nT) + (size_t)rr * nT;
      } else {
        resrow = crow;
      }
#pragma unroll
      for (int ni = 0; ni < 4; ++ni) {
        const int col = colb + ni * 16;
        if (col < nT)
          crow[col] = fmaxf(acc[mi][ni][r] + bv[ni], 0.f) + resrow[col];
      }
    }
  }
}

// ---------------- W prep: Wt[i][n][k] = bf16(gcn_W[i][k][n]), zero-padded ------
__global__ void wprep_k(const float* __restrict__ W, unsigned short* __restrict__ Wt)
{
  __shared__ float t[32][33];
  const int i = blockIdx.z;
  const int k0 = blockIdx.x * 32;
  const int n0 = blockIdx.y * 32;
  const int tx = threadIdx.x, ty = threadIdx.y;   // 32 x 8
#pragma unroll
  for (int r = 0; r < 32; r += 8) {
    int k = k0 + ty + r, n = n0 + tx;
    t[ty + r][tx] = (k < nT && n < nT) ? W[(size_t)i * nT * nT + (size_t)k * nT + n] : 0.f;
  }
  __syncthreads();
#pragma unroll
  for (int r = 0; r < 32; r += 8) {
    int n = n0 + ty + r, k = k0 + tx;
    Wt[(size_t)i * KP * KP + (size_t)n * KP + k] = f2bf(t[tx][ty + r]);
  }
}

// ---------------- SE gate (gap == 1/R identically) -----------------------------
__global__ void gate_k(const float* __restrict__ w1, const float* __restrict__ b1,
                       const float* __restrict__ w2, const float* __restrict__ b2,
                       float* gate)
{
  if (threadIdx.x == 0 && blockIdx.x == 0) {
    float h1[4];
    const float gap = 1.0f / 400.0f;
#pragma unroll
    for (int i = 0; i < 4; ++i) {
      float s = b1[i];
      for (int h = 0; h < 8; ++h) s += gap * w1[h * 4 + i];
      h1[i] = fmaxf(s, 0.f);
    }
#pragma unroll
    for (int h = 0; h < 8; ++h) {
      float s = b2[h];
      for (int i = 0; i < 4; ++i) s += h1[i] * w2[i * 8 + h];
      gate[h] = 1.f / (1.f + expf(-s));
    }
  }
}

// ---------------- fused scores -> relu -> softmax -> gate -> stable-rank mask --
// v2: 128-col K stages (4 vs 7), 4x2 register tiles (8 FMA per LDS read),
// XOR-swizzled K tile (2-way max), wave-uniform Q broadcasts, sc stride 424.
__global__ __launch_bounds__(256) void attn_k(
    const float* __restrict__ qk, const float* __restrict__ gate,
    float* __restrict__ adjval, int* __restrict__ adjcol)
{
  __shared__ float Qs[16][68];     //  4.3 KB
  __shared__ float Ks[128 * 64];   // 32.0 KB, chunk c of row r at c^(r&15)
  __shared__ float sc[16][424];    // 27.1 KB, stride 424 -> 2-way on 16-lane phase

  const int tid = threadIdx.x;
  const int bh = blockIdx.x / 25;
  const int rt = (blockIdx.x % 25) * 16;
  const int b = bh / nH;
  const int h = bh % nH;
  const float* qkb = qk + (size_t)b * nR * HQ + h * nQ;

  {  // Q stage: one float4 per thread
    int r = tid >> 4;
    int q = (tid & 15) << 2;
    *(float4*)&Qs[r][q] = *(const float4*)(qkb + (size_t)(rt + r) * HQ + q);
  }

  const int ty = tid >> 6;   // wave id: whole wave shares ty -> Q reads broadcast
  const int tx = tid & 63;

  for (int st = 0; st < 4; ++st) {
    const int sn = st * 128;
    const int cnt = (nR - sn < 128) ? (nR - sn) : 128;   // 128,128,128,16
    __syncthreads();
    for (int i = tid; i < cnt * 16; i += 256) {
      const int row = i >> 4, c4 = i & 15;
      float4 v = *(const float4*)(qkb + (size_t)(sn + row) * HQ + (c4 << 2));
      *(float4*)&Ks[row * 64 + ((c4 ^ (row & 15)) << 2)] = v;
    }
    __syncthreads();

    const int c0 = tx, c1 = tx + 64;
    const bool a0 = (c0 < cnt);
    const bool a1 = (c1 < cnt);
    if (a0) {
      float acc[4][2] = {};
#pragma unroll
      for (int k4 = 0; k4 < 16; ++k4) {
        float4 k0v = *(const float4*)&Ks[c0 * 64 + ((k4 ^ (c0 & 15)) << 2)];
        float4 k1v = {0.f, 0.f, 0.f, 0.f};
        if (a1) k1v = *(const float4*)&Ks[c1 * 64 + ((k4 ^ (c1 & 15)) << 2)];
#pragma unroll
        for (int i = 0; i < 4; ++i) {
          float4 qv = *(const float4*)&Qs[ty * 4 + i][k4 << 2];
          acc[i][0] += qv.x * k0v.x + qv.y * k0v.y + qv.z * k0v.z + qv.w * k0v.w;
          acc[i][1] += qv.x * k1v.x + qv.y * k1v.y + qv.z * k1v.z + qv.w * k1v.w;
        }
      }
#pragma unroll
      for (int i = 0; i < 4; ++i) {
        sc[ty * 4 + i][sn + c0] = fmaxf(acc[i][0] * 0.125f, 0.f);
        if (a1) sc[ty * 4 + i][sn + c1] = fmaxf(acc[i][1] * 0.125f, 0.f);
      }
    }
  }
  __syncthreads();

  // softmax over each row: 16 threads per row (proven phase, unchanged)
  const int tr = tid >> 4;
  const int tl = tid & 15;
  float m = 0.f;
  for (int j = tl; j < nR; j += 16) m = fmaxf(m, sc[tr][j]);
#pragma unroll
  for (int o = 8; o > 0; o >>= 1) m = fmaxf(m, __shfl_xor(m, o));
  float ssum = 0.f;
  for (int j = tl; j < nR; j += 16) {
    float e = expf(sc[tr][j] - m);
    sc[tr][j] = e;
    ssum += e;
  }
#pragma unroll
  for (int o = 8; o > 0; o >>= 1) ssum += __shfl_xor(ssum, o);
  const float g = gate[h];
  for (int j = tl; j < nR; j += 16) sc[tr][j] = (sc[tr][j] / ssum) * g;
  __syncthreads();

  // stable-argsort ranks of special columns {0,16..20}
  const int csp[6] = {0, 16, 17, 18, 19, 20};
  float vc[6];
#pragma unroll
  for (int i = 0; i < 6; ++i) vc[i] = sc[tr][csp[i]];
  int rk[6] = {0, 0, 0, 0, 0, 0};
  for (int j = tl; j < nR; j += 16) {
    float vj = sc[tr][j];
#pragma unroll
    for (int i = 0; i < 6; ++i)
      rk[i] += (vj < vc[i]) ? 1 : ((vj == vc[i] && j < csp[i]) ? 1 : 0);
  }
#pragma unroll
  for (int i = 0; i < 6; ++i)
#pragma unroll
    for (int o = 8; o > 0; o >>= 1) rk[i] += __shfl_xor(rk[i], o);

  if (tl == 0) {
    const int rg = rt + tr;
    const size_t base = ((size_t)bh * nR + rg) * 8;
    bool dup = false;
#pragma unroll
    for (int i = 0; i < 6; ++i) {
      int p = rk[i];
      adjcol[base + i] = p;
      adjval[base + i] = sc[tr][p];
      dup = dup || (p == rg);
    }
    adjcol[base + 6] = rg;
    adjval[base + 6] = dup ? 0.f : sc[tr][rg];
    adjcol[base + 7] = rg;
    adjval[base + 7] = 0.f;
  }
}

// ---------------- sparse msg via LDS-staged feats column-chunks ----------------
__global__ __launch_bounds__(256) void spmsg_k(
    const int* __restrict__ adjcol, const float* __restrict__ adjval,
    const float* __restrict__ feats, const float* __restrict__ x, int first,
    unsigned short* __restrict__ msg)
{
  __shared__ float fs[400 * 36];   // 57.6 KB, row stride 36 floats

  const int tid = threadIdx.x;
  const int bh = blockIdx.y;
  const int c0 = blockIdx.x * 32;
  const float* src = first ? (x + (size_t)(bh >> 3) * (nR * nT))
                           : (feats + (size_t)bh * nR * nT);

  for (int i = tid; i < 3200; i += 256) {
    const int r = i >> 3, c4 = i & 7;
    const int c = c0 + c4 * 4;
    float4 v = {0.f, 0.f, 0.f, 0.f};
    if (c < 400) v = *(const float4*)(src + (size_t)r * nT + c);
    *(float4*)&fs[r * 36 + c4 * 4] = v;
  }
  __syncthreads();

  const int* ac = adjcol + (size_t)bh * nR * 8;
  const float* av = adjval + (size_t)bh * nR * 8;
  for (int i = tid; i < 3200; i += 256) {
    const int r = i >> 3, c4 = i & 7;
    float4 acc = {0.f, 0.f, 0.f, 0.f};
#pragma unroll
    for (int j = 0; j < 7; ++j) {
      const int col = ac[r * 8 + j];
      const float val = av[r * 8 + j];
      float4 v = *(const float4*)&fs[col * 36 + c4 * 4];
      acc.x += val * v.x; acc.y += val * v.y;
      acc.z += val * v.z; acc.w += val * v.w;
    }
    unsigned short* o = msg + ((size_t)bh * nR + r) * KP + c0 + c4 * 4;
    *(ushort4*)o = make_ushort4(f2bf(acc.x), f2bf(acc.y), f2bf(acc.z), f2bf(acc.w));
  }
}

// ---------------- head fusion ---------------------------------------------------
__global__ void hfuse_k(const float* __restrict__ feats, const float* __restrict__ fw,
                        const float* __restrict__ fb, float* __restrict__ fused)
{
  size_t i = (size_t)blockIdx.x * 256 + threadIdx.x;
  constexpr size_t tot4 = (size_t)nB * nR * nT / 4;
  if (i >= tot4) return;
  size_t b = i / (nR * nT / 4);
  size_t rem = i % (nR * nT / 4);
  float fbv = fb[0];
  float4 acc = {fbv, fbv, fbv, fbv};
#pragma unroll
  for (int h = 0; h < nH; ++h) {
    float w = fw[h];
    float4 v = ((const float4*)feats)[(b * nH + h) * (nR * nT / 4) + rem];
    acc.x += w * v.x; acc.y += w * v.y; acc.z += w * v.z; acc.w += w * v.w;
  }
  ((float4*)fused)[i] = acc;
}

}  // namespace

extern "C" void kernel_launch(void* const* d_in, const int* in_sizes, int n_in,
                              void* d_out, int out_size, void* d_ws, size_t ws_size,
                              hipStream_t stream)
{
  (void)in_sizes; (void)n_in; (void)out_size; (void)ws_size;
  const float* x    = (const float*)d_in[0];
  const float* Wk   = (const float*)d_in[1];
  const float* bk   = (const float*)d_in[2];
  const float* seW1 = (const float*)d_in[3];
  const float* seb1 = (const float*)d_in[4];
  const float* seW2 = (const float*)d_in[5];
  const float* seb2 = (const float*)d_in[6];
  const float* gcnW = (const float*)d_in[7];
  const float* gcnb = (const float*)d_in[8];
  const float* fw   = (const float*)d_in[9];
  const float* fb   = (const float*)d_in[10];
  const float* mW1  = (const float*)d_in[11];
  const float* mb1  = (const float*)d_in[12];
  const float* mW2  = (const float*)d_in[13];
  const float* mb2  = (const float*)d_in[14];
  const float* mW3  = (const float*)d_in[15];
  const float* mb3  = (const float*)d_in[16];
  const float* mW4  = (const float*)d_in[17];
  const float* mb4  = (const float*)d_in[18];
  float* out = (float*)d_out;

  // workspace (float units), total ~130.6 MB
  float* ws     = (float*)d_ws;
  float* adjval = ws;
  int*   adjcol = (int*)(adjval + 409600);
  float* gate   = (float*)(adjcol + 409600);
  unsigned short* Wt = (unsigned short*)(gate + 64);          // 8*416*416 shorts
  float* feats  = gate + 64 + (size_t)8 * KP * KP / 2;        // 51200*400 f
  float* big    = feats + (size_t)51200 * 400;
  float* qk     = big;                                        // 6400*512 f
  unsigned short* msg = (unsigned short*)big;                 // 51200*416 sh
  float* fused  = big;                                        // aliases dead msg
  float* h1     = fused + (size_t)6400 * 400;
  float* h2     = h1 + (size_t)6400 * 256;
  float* h3     = h2 + (size_t)6400 * 128;

  // 0. gcn_W -> bf16, transposed (n-major), zero-padded to 416x416
  wprep_k<<<dim3(13, 13, 8), dim3(32, 8), 0, stream>>>(gcnW, Wt);

  // 1. qk = x @ Wk + bk  (64x64 tiles: 800 blocks for occupancy)
  gemm_k<64, 64, 16, 4, 4, false><<<dim3(8, 100), 256, 0, stream>>>(
      x, Wk, bk, qk, 6400, 512, 400);

  // 2. SE gate
  gate_k<<<1, 64, 0, stream>>>(seW1, seb1, seW2, seb2, gate);

  // 3. attention -> 7-sparse adjacency (fp32, rank-exact)
  attn_k<<<BH * 25, 256, 0, stream>>>(qk, gate, adjval, adjcol);

  // 4. 8x GCN: LDS-gather spmsg + bf16 MFMA GEMM (layer 0 sources x directly)
  for (int i = 0; i < 8; ++i) {
    spmsg_k<<<dim3(13, BH), 256, 0, stream>>>(adjcol, adjval, feats, x,
                                              (i == 0) ? 1 : 0, msg);
    gcn_gemm<<<dim3(4, 400), 256, 0, stream>>>(
        msg, Wt + (size_t)i * KP * KP, gcnb + (size_t)i * nT, feats, x,
        (i == 0) ? 1 : 0);
  }

  // 5. fuse heads
  hfuse_k<<<2500, 256, 0, stream>>>(feats, fw, fb, fused);

  // 6-9. MLP head (fp32)
  gemm_k<64, 64, 16, 4, 4, true><<<dim3(4, 100), 256, 0, stream>>>(
      fused, mW1, mb1, h1, 6400, 256, 400);
  gemm_k<64, 64, 16, 4, 4, true><<<dim3(2, 100), 256, 0, stream>>>(
      h1, mW2, mb2, h2, 6400, 128, 256);
  gemm_k<64, 64, 16, 4, 4, true><<<dim3(1, 100), 256, 0, stream>>>(
      h2, mW3, mb3, h3, 6400, 64, 128);
  gemm_k<64, 64, 16, 4, 4, true><<<dim3(1, 100), 256, 0, stream>>>(
      h3, mW4, mb4, out, 6400, 5, 64);
}

// Round 7
// 1632.863 us; speedup vs baseline: 17.8565x; 1.0777x over previous
//
#include <hip/hip_runtime.h>
#include <math.h>

namespace {

constexpr int nB = 16, nR = 400, nT = 400, nH = 8, nQ = 64;
constexpr int BH = nB * nH;   // 128
constexpr int HQ = nH * nQ;   // 512
constexpr int KP = 416;       // padded K for bf16 GCN GEMM (13 x 32)

typedef __attribute__((ext_vector_type(8))) short short8;
typedef __attribute__((ext_vector_type(4))) float floatx4;

__device__ __forceinline__ unsigned short f2bf(float f) {
  unsigned int u = __float_as_uint(f);
  unsigned int r = (u + 0x7fffu + ((u >> 16) & 1u)) >> 16;
  return (unsigned short)r;
}

__device__ __forceinline__ void gload16(const void* g, void* l) {
  __builtin_amdgcn_global_load_lds(
      (const __attribute__((address_space(1))) unsigned int*)g,
      (__attribute__((address_space(3))) unsigned int*)l, 16, 0, 0);
}

// ---------------- generic fp32 GEMM: C = act(A@W + bias) ----------------
template<int BM, int BN, int BK, int TM, int TN, bool RELU>
__global__ __launch_bounds__(256) void gemm_k(
    const float* __restrict__ A, const float* __restrict__ W,
    const float* __restrict__ bias,
    float* C, int M, int N, int K)
{
  constexpr int NT = (BM / TM) * (BN / TN);
  static_assert(NT == 256, "block must be 256 threads");
  __shared__ float As[BK][BM + 4];
  __shared__ float Bs[BK][BN + 4];
  const int tid = threadIdx.x;
  const int bm = blockIdx.y * BM;
  const int bn = blockIdx.x * BN;
  const int tx = tid % (BN / TN);
  const int ty = tid / (BN / TN);
  const bool n4ok = ((N & 3) == 0);

  float acc[TM][TN];
#pragma unroll
  for (int i = 0; i < TM; ++i)
#pragma unroll
    for (int j = 0; j < TN; ++j) acc[i][j] = 0.f;

  for (int kt = 0; kt < K; kt += BK) {
#pragma unroll
    for (int i = 0; i < (BM * BK) / (NT * 4); ++i) {
      int flat = (tid + i * NT) * 4;
      int m = flat / BK;
      int k = flat % BK;
      float4 v = *(const float4*)(A + (size_t)(bm + m) * K + kt + k);
      As[k + 0][m] = v.x; As[k + 1][m] = v.y;
      As[k + 2][m] = v.z; As[k + 3][m] = v.w;
    }
#pragma unroll
    for (int i = 0; i < (BK * BN) / (NT * 4); ++i) {
      int flat = (tid + i * NT) * 4;
      int k = flat / BN;
      int n = flat % BN;
      int gn = bn + n;
      float4 v;
      if (n4ok && gn + 3 < N) {
        v = *(const float4*)(W + (size_t)(kt + k) * N + gn);
      } else {
        v.x = (gn + 0 < N) ? W[(size_t)(kt + k) * N + gn + 0] : 0.f;
        v.y = (gn + 1 < N) ? W[(size_t)(kt + k) * N + gn + 1] : 0.f;
        v.z = (gn + 2 < N) ? W[(size_t)(kt + k) * N + gn + 2] : 0.f;
        v.w = (gn + 3 < N) ? W[(size_t)(kt + k) * N + gn + 3] : 0.f;
      }
      *(float4*)&Bs[k][n] = v;
    }
    __syncthreads();
#pragma unroll
    for (int k = 0; k < BK; ++k) {
      float a[TM], b[TN];
#pragma unroll
      for (int i = 0; i < TM; i += 4)
        *(float4*)&a[i] = *(const float4*)&As[k][ty * TM + i];
#pragma unroll
      for (int j = 0; j < TN; j += 4)
        *(float4*)&b[j] = *(const float4*)&Bs[k][tx * TN + j];
#pragma unroll
      for (int i = 0; i < TM; ++i)
#pragma unroll
        for (int j = 0; j < TN; ++j) acc[i][j] += a[i] * b[j];
    }
    __syncthreads();
  }

#pragma unroll
  for (int i = 0; i < TM; ++i) {
    const int gm = bm + ty * TM + i;
    float* crow = C + (size_t)gm * N;
#pragma unroll
    for (int j = 0; j < TN; j += 4) {
      const int gn = bn + tx * TN + j;
      if (n4ok && gn + 3 < N) {
        float4 bv = *(const float4*)(bias + gn);
        float4 v;
        v.x = acc[i][j + 0] + bv.x; v.y = acc[i][j + 1] + bv.y;
        v.z = acc[i][j + 2] + bv.z; v.w = acc[i][j + 3] + bv.w;
        if (RELU) {
          v.x = fmaxf(v.x, 0.f); v.y = fmaxf(v.y, 0.f);
          v.z = fmaxf(v.z, 0.f); v.w = fmaxf(v.w, 0.f);
        }
        *(float4*)(crow + gn) = v;
      } else {
#pragma unroll
        for (int jj = 0; jj < 4; ++jj) {
          int gnn = gn + jj;
          if (gnn < N) {
            float v = acc[i][j + jj] + bias[gnn];
            if (RELU) v = fmaxf(v, 0.f);
            crow[gnn] = v;
          }
        }
      }
    }
  }
}

// ---------------- bf16 MFMA GEMM for GCN layers (128x128 tile, KP=416) --------
__global__ __launch_bounds__(256) void gcn_gemm(
    const unsigned short* __restrict__ A,
    const unsigned short* __restrict__ Bt,
    const float* __restrict__ bias,
    float* __restrict__ C,
    const float* __restrict__ x, int first)
{
  __shared__ __align__(128) unsigned short As[128 * 32];  // 8 KB
  __shared__ __align__(128) unsigned short Bs[128 * 32];  // 8 KB

  const int tid = threadIdx.x;
  const int lane = tid & 63;
  const int wave = tid >> 6;
  const int bm = blockIdx.y * 128;
  const int bn = blockIdx.x * 128;        // covers 512 cols; >=400 is pad
  const int wm = (wave & 1) * 64;
  const int wn = (wave >> 1) * 64;

  floatx4 acc[4][4] = {};

  const int r0 = wave * 32 + (lane >> 2);
  const int c0 = (lane & 3) * 8;
  const unsigned short* Ag0 = A + (size_t)(bm + r0) * KP + c0;
  const unsigned short* Ag1 = A + (size_t)(bm + r0 + 16) * KP + c0;
  int br0 = bn + r0;      if (br0 > 415) br0 = 415;  // zero-pad row of Wt
  int br1 = bn + r0 + 16; if (br1 > 415) br1 = 415;
  const unsigned short* Bg0 = Bt + (size_t)br0 * KP + c0;
  const unsigned short* Bg1 = Bt + (size_t)br1 * KP + c0;
  unsigned short* Al0 = As + (wave * 2) * 512;
  unsigned short* Al1 = As + (wave * 2 + 1) * 512;
  unsigned short* Bl0 = Bs + (wave * 2) * 512;
  unsigned short* Bl1 = Bs + (wave * 2 + 1) * 512;

  const int fr = lane & 15;
  const int fkk = (lane >> 4) * 8;

  for (int kt = 0; kt < KP; kt += 32) {
    gload16(Ag0 + kt, Al0);
    gload16(Ag1 + kt, Al1);
    gload16(Bg0 + kt, Bl0);
    gload16(Bg1 + kt, Bl1);
    __syncthreads();

    short8 a[4], b[4];
#pragma unroll
    for (int mi = 0; mi < 4; ++mi)
      a[mi] = *(const short8*)(As + (wm + mi * 16 + fr) * 32 + fkk);
#pragma unroll
    for (int ni = 0; ni < 4; ++ni)
      b[ni] = *(const short8*)(Bs + (wn + ni * 16 + fr) * 32 + fkk);
#pragma unroll
    for (int mi = 0; mi < 4; ++mi)
#pragma unroll
      for (int ni = 0; ni < 4; ++ni)
        acc[mi][ni] = __builtin_amdgcn_mfma_f32_16x16x32_bf16(
            a[mi], b[ni], acc[mi][ni], 0, 0, 0);
    __syncthreads();
  }

  const int colb = bn + wn + (lane & 15);
  float bv[4];
#pragma unroll
  for (int ni = 0; ni < 4; ++ni) {
    const int col = colb + ni * 16;
    bv[ni] = (col < nT) ? bias[col] : 0.f;
  }

#pragma unroll
  for (int mi = 0; mi < 4; ++mi) {
    const int row0 = bm + wm + mi * 16 + (lane >> 4) * 4;
#pragma unroll
    for (int r = 0; r < 4; ++r) {
      const int gr = row0 + r;
      float* crow = C + (size_t)gr * nT;
      const float* resrow;
      if (first) {
        const int bh = gr / nR;
        const int rr = gr - bh * nR;
        resrow = x + (size_t)(bh >> 3) * (nR * nT) + (size_t)rr * nT;
      } else {
        resrow = crow;
      }
#pragma unroll
      for (int ni = 0; ni < 4; ++ni) {
        const int col = colb + ni * 16;
        if (col < nT)
          crow[col] = fmaxf(acc[mi][ni][r] + bv[ni], 0.f) + resrow[col];
      }
    }
  }
}

// ---------------- W prep: Wt[i][n][k] = bf16(gcn_W[i][k][n]), zero-padded ------
__global__ void wprep_k(const float* __restrict__ W, unsigned short* __restrict__ Wt)
{
  __shared__ float t[32][33];
  const int i = blockIdx.z;
  const int k0 = blockIdx.x * 32;
  const int n0 = blockIdx.y * 32;
  const int tx = threadIdx.x, ty = threadIdx.y;   // 32 x 8
#pragma unroll
  for (int r = 0; r < 32; r += 8) {
    int k = k0 + ty + r, n = n0 + tx;
    t[ty + r][tx] = (k < nT && n < nT) ? W[(size_t)i * nT * nT + (size_t)k * nT + n] : 0.f;
  }
  __syncthreads();
#pragma unroll
  for (int r = 0; r < 32; r += 8) {
    int n = n0 + ty + r, k = k0 + tx;
    Wt[(size_t)i * KP * KP + (size_t)n * KP + k] = f2bf(t[tx][ty + r]);
  }
}

// ---------------- SE gate (gap == 1/R identically) -----------------------------
__global__ void gate_k(const float* __restrict__ w1, const float* __restrict__ b1,
                       const float* __restrict__ w2, const float* __restrict__ b2,
                       float* gate)
{
  if (threadIdx.x == 0 && blockIdx.x == 0) {
    float h1[4];
    const float gap = 1.0f / 400.0f;
#pragma unroll
    for (int i = 0; i < 4; ++i) {
      float s = b1[i];
      for (int h = 0; h < 8; ++h) s += gap * w1[h * 4 + i];
      h1[i] = fmaxf(s, 0.f);
    }
#pragma unroll
    for (int h = 0; h < 8; ++h) {
      float s = b2[h];
      for (int i = 0; i < 4; ++i) s += h1[i] * w2[i * 8 + h];
      gate[h] = 1.f / (1.f + expf(-s));
    }
  }
}

// ---------------- batched QK^T scores: sc = relu((Q@K^T)/8) --------------------
// grid (7,7,128): (n-tile, m-tile, bh). K=64 staged once, one barrier.
// LDS tiles transposed (Qt[k][m], Kt[k][n]): a-reads broadcast, b-reads 2-way.
__global__ __launch_bounds__(256) void qkscore_k(
    const float* __restrict__ qk, float* __restrict__ sc)
{
  __shared__ float Qs[64][68];   // Qs[k][m]
  __shared__ float Ks[64][68];   // Ks[k][n]

  const int tid = threadIdx.x;
  const int bh = blockIdx.z;
  const int b = bh >> 3, h = bh & 7;
  const int bm = blockIdx.y * 64;
  const int bn = blockIdx.x * 64;
  const float* qkb = qk + (size_t)b * nR * HQ + h * nQ;

  for (int i = tid; i < 1024; i += 256) {
    const int r = i >> 4;            // local row 0..63
    const int c4 = (i & 15) << 2;    // k offset 0,4,...,60
    int gr = bm + r; if (gr > 399) gr = 399;   // clamp: stores guarded below
    float4 v = *(const float4*)(qkb + (size_t)gr * HQ + c4);
    Qs[c4 + 0][r] = v.x; Qs[c4 + 1][r] = v.y;
    Qs[c4 + 2][r] = v.z; Qs[c4 + 3][r] = v.w;
    int gs = bn + r; if (gs > 399) gs = 399;
    float4 w = *(const float4*)(qkb + (size_t)gs * HQ + c4);
    Ks[c4 + 0][r] = w.x; Ks[c4 + 1][r] = w.y;
    Ks[c4 + 2][r] = w.z; Ks[c4 + 3][r] = w.w;
  }
  __syncthreads();

  const int tx = tid & 15;    // n/4
  const int ty = tid >> 4;    // m/4
  float acc[4][4] = {};
#pragma unroll
  for (int k = 0; k < 64; ++k) {
    float4 a = *(const float4*)&Qs[k][ty * 4];
    float4 bv = *(const float4*)&Ks[k][tx * 4];
    acc[0][0] += a.x * bv.x; acc[0][1] += a.x * bv.y; acc[0][2] += a.x * bv.z; acc[0][3] += a.x * bv.w;
    acc[1][0] += a.y * bv.x; acc[1][1] += a.y * bv.y; acc[1][2] += a.y * bv.z; acc[1][3] += a.y * bv.w;
    acc[2][0] += a.z * bv.x; acc[2][1] += a.z * bv.y; acc[2][2] += a.z * bv.z; acc[2][3] += a.z * bv.w;
    acc[3][0] += a.w * bv.x; acc[3][1] += a.w * bv.y; acc[3][2] += a.w * bv.z; acc[3][3] += a.w * bv.w;
  }

  const int gc = bn + tx * 4;
  if (gc < 400) {   // 400 % 4 == 0: float4 all-or-nothing
#pragma unroll
    for (int i = 0; i < 4; ++i) {
      const int gr = bm + ty * 4 + i;
      if (gr < 400) {
        float4 o;
        o.x = fmaxf(acc[i][0] * 0.125f, 0.f);
        o.y = fmaxf(acc[i][1] * 0.125f, 0.f);
        o.z = fmaxf(acc[i][2] * 0.125f, 0.f);
        o.w = fmaxf(acc[i][3] * 0.125f, 0.f);
        *(float4*)(sc + ((size_t)bh * nR + gr) * 400 + gc) = o;
      }
    }
  }
}

// ---------------- softmax + gate + stable-rank mask -> sparse adj --------------
// One wave per row (400 cols). Coalesced row read, 64-lane shuffle reductions,
// per-wave LDS row cache for the rank->value gather.
__global__ __launch_bounds__(256) void rankadj_k(
    const float* __restrict__ sc, const float* __restrict__ gate,
    float* __restrict__ adjval, int* __restrict__ adjcol)
{
  __shared__ float rowbuf[4][408];

  const int wave = threadIdx.x >> 6;
  const int lane = threadIdx.x & 63;
  const int row = blockIdx.x * 4 + wave;    // 0..51199
  const int bh = row / nR;
  const int r = row - bh * nR;
  const float* srow = sc + (size_t)row * 400;

  float v[7];
  bool valid[7];
#pragma unroll
  for (int it = 0; it < 7; ++it) {
    const int j = lane + it * 64;
    valid[it] = (j < 400);
    v[it] = valid[it] ? srow[j] : 0.f;
  }

  // max (relu'd values >= 0, so init 0 is safe)
  float m = 0.f;
#pragma unroll
  for (int it = 0; it < 7; ++it) m = fmaxf(m, v[it]);
#pragma unroll
  for (int o = 32; o > 0; o >>= 1) m = fmaxf(m, __shfl_xor(m, o));

  float e[7];
  float s = 0.f;
#pragma unroll
  for (int it = 0; it < 7; ++it) {
    e[it] = valid[it] ? expf(v[it] - m) : 0.f;
    s += e[it];
  }
#pragma unroll
  for (int o = 32; o > 0; o >>= 1) s += __shfl_xor(s, o);

  const float g = gate[bh & 7];
  float val[7];
#pragma unroll
  for (int it = 0; it < 7; ++it) val[it] = (e[it] / s) * g;  // same expr as before

#pragma unroll
  for (int it = 0; it < 7; ++it)
    if (valid[it]) rowbuf[wave][lane + it * 64] = val[it];
  __syncthreads();

  // stable-argsort ranks of special columns {0,16..20}
  const int csp[6] = {0, 16, 17, 18, 19, 20};
  float vc[6];
#pragma unroll
  for (int i = 0; i < 6; ++i) vc[i] = rowbuf[wave][csp[i]];
  int rk[6] = {0, 0, 0, 0, 0, 0};
#pragma unroll
  for (int it = 0; it < 7; ++it) {
    if (valid[it]) {
      const int j = lane + it * 64;
      const float vj = val[it];
#pragma unroll
      for (int i = 0; i < 6; ++i)
        rk[i] += (vj < vc[i]) ? 1 : ((vj == vc[i] && j < csp[i]) ? 1 : 0);
    }
  }
#pragma unroll
  for (int i = 0; i < 6; ++i)
#pragma unroll
    for (int o = 32; o > 0; o >>= 1) rk[i] += __shfl_xor(rk[i], o);

  if (lane == 0) {
    const size_t base = (size_t)row * 8;
    bool dup = false;
#pragma unroll
    for (int i = 0; i < 6; ++i) {
      const int p = rk[i];
      adjcol[base + i] = p;
      adjval[base + i] = rowbuf[wave][p];
      dup = dup || (p == r);
    }
    adjcol[base + 6] = r;
    adjval[base + 6] = dup ? 0.f : rowbuf[wave][r];
    adjcol[base + 7] = r;
    adjval[base + 7] = 0.f;
  }
}

// ---------------- sparse msg via LDS-staged feats column-chunks ----------------
__global__ __launch_bounds__(256) void spmsg_k(
    const int* __restrict__ adjcol, const float* __restrict__ adjval,
    const float* __restrict__ feats, const float* __restrict__ x, int first,
    unsigned short* __restrict__ msg)
{
  __shared__ float fs[400 * 36];   // 57.6 KB, row stride 36 floats

  const int tid = threadIdx.x;
  const int bh = blockIdx.y;
  const int c0 = blockIdx.x * 32;
  const float* src = first ? (x + (size_t)(bh >> 3) * (nR * nT))
                           : (feats + (size_t)bh * nR * nT);

  for (int i = tid; i < 3200; i += 256) {
    const int r = i >> 3, c4 = i & 7;
    const int c = c0 + c4 * 4;
    float4 v = {0.f, 0.f, 0.f, 0.f};
    if (c < 400) v = *(const float4*)(src + (size_t)r * nT + c);
    *(float4*)&fs[r * 36 + c4 * 4] = v;
  }
  __syncthreads();

  const int* ac = adjcol + (size_t)bh * nR * 8;
  const float* av = adjval + (size_t)bh * nR * 8;
  for (int i = tid; i < 3200; i += 256) {
    const int r = i >> 3, c4 = i & 7;
    float4 acc = {0.f, 0.f, 0.f, 0.f};
#pragma unroll
    for (int j = 0; j < 7; ++j) {
      const int col = ac[r * 8 + j];
      const float val = av[r * 8 + j];
      float4 v = *(const float4*)&fs[col * 36 + c4 * 4];
      acc.x += val * v.x; acc.y += val * v.y;
      acc.z += val * v.z; acc.w += val * v.w;
    }
    unsigned short* o = msg + ((size_t)bh * nR + r) * KP + c0 + c4 * 4;
    *(ushort4*)o = make_ushort4(f2bf(acc.x), f2bf(acc.y), f2bf(acc.z), f2bf(acc.w));
  }
}

// ---------------- head fusion ---------------------------------------------------
__global__ void hfuse_k(const float* __restrict__ feats, const float* __restrict__ fw,
                        const float* __restrict__ fb, float* __restrict__ fused)
{
  size_t i = (size_t)blockIdx.x * 256 + threadIdx.x;
  constexpr size_t tot4 = (size_t)nB * nR * nT / 4;
  if (i >= tot4) return;
  size_t b = i / (nR * nT / 4);
  size_t rem = i % (nR * nT / 4);
  float fbv = fb[0];
  float4 acc = {fbv, fbv, fbv, fbv};
#pragma unroll
  for (int h = 0; h < nH; ++h) {
    float w = fw[h];
    float4 v = ((const float4*)feats)[(b * nH + h) * (nR * nT / 4) + rem];
    acc.x += w * v.x; acc.y += w * v.y; acc.z += w * v.z; acc.w += w * v.w;
  }
  ((float4*)fused)[i] = acc;
}

}  // namespace

extern "C" void kernel_launch(void* const* d_in, const int* in_sizes, int n_in,
                              void* d_out, int out_size, void* d_ws, size_t ws_size,
                              hipStream_t stream)
{
  (void)in_sizes; (void)n_in; (void)out_size; (void)ws_size;
  const float* x    = (const float*)d_in[0];
  const float* Wk   = (const float*)d_in[1];
  const float* bk   = (const float*)d_in[2];
  const float* seW1 = (const float*)d_in[3];
  const float* seb1 = (const float*)d_in[4];
  const float* seW2 = (const float*)d_in[5];
  const float* seb2 = (const float*)d_in[6];
  const float* gcnW = (const float*)d_in[7];
  const float* gcnb = (const float*)d_in[8];
  const float* fw   = (const float*)d_in[9];
  const float* fb   = (const float*)d_in[10];
  const float* mW1  = (const float*)d_in[11];
  const float* mb1  = (const float*)d_in[12];
  const float* mW2  = (const float*)d_in[13];
  const float* mb2  = (const float*)d_in[14];
  const float* mW3  = (const float*)d_in[15];
  const float* mb3  = (const float*)d_in[16];
  const float* mW4  = (const float*)d_in[17];
  const float* mb4  = (const float*)d_in[18];
  float* out = (float*)d_out;

  // workspace (float units), total ~130.6 MB
  float* ws     = (float*)d_ws;
  float* adjval = ws;
  int*   adjcol = (int*)(adjval + 409600);
  float* gate   = (float*)(adjcol + 409600);
  unsigned short* Wt = (unsigned short*)(gate + 64);          // 8*416*416 shorts
  float* feats  = gate + 64 + (size_t)8 * KP * KP / 2;        // 51200*400 f
  float* scores = feats;                                      // aliases feats (dead until GCN L0)
  float* big    = feats + (size_t)51200 * 400;
  float* qk     = big;                                        // 6400*512 f
  unsigned short* msg = (unsigned short*)big;                 // 51200*416 sh
  float* fused  = big;                                        // aliases dead msg
  float* h1     = fused + (size_t)6400 * 400;
  float* h2     = h1 + (size_t)6400 * 256;
  float* h3     = h2 + (size_t)6400 * 128;

  // 0. gcn_W -> bf16, transposed (n-major), zero-padded to 416x416
  wprep_k<<<dim3(13, 13, 8), dim3(32, 8), 0, stream>>>(gcnW, Wt);

  // 1. qk = x @ Wk + bk
  gemm_k<64, 64, 16, 4, 4, false><<<dim3(8, 100), 256, 0, stream>>>(
      x, Wk, bk, qk, 6400, 512, 400);

  // 2. SE gate
  gate_k<<<1, 64, 0, stream>>>(seW1, seb1, seW2, seb2, gate);

  // 3a. batched QK^T -> relu -> scores [51200,400] (in feats region)
  qkscore_k<<<dim3(7, 7, 128), 256, 0, stream>>>(qk, scores);

  // 3b. softmax+gate+rank -> 7-sparse adjacency (one wave per row)
  rankadj_k<<<12800, 256, 0, stream>>>(scores, gate, adjval, adjcol);

  // 4. 8x GCN: LDS-gather spmsg + bf16 MFMA GEMM (layer 0 sources x directly)
  for (int i = 0; i < 8; ++i) {
    spmsg_k<<<dim3(13, BH), 256, 0, stream>>>(adjcol, adjval, feats, x,
                                              (i == 0) ? 1 : 0, msg);
    gcn_gemm<<<dim3(4, 400), 256, 0, stream>>>(
        msg, Wt + (size_t)i * KP * KP, gcnb + (size_t)i * nT, feats, x,
        (i == 0) ? 1 : 0);
  }

  // 5. fuse heads
  hfuse_k<<<2500, 256, 0, stream>>>(feats, fw, fb, fused);

  // 6-9. MLP head (fp32)
  gemm_k<64, 64, 16, 4, 4, true><<<dim3(4, 100), 256, 0, stream>>>(
      fused, mW1, mb1, h1, 6400, 256, 400);
  gemm_k<64, 64, 16, 4, 4, true><<<dim3(2, 100), 256, 0, stream>>>(
      h1, mW2, mb2, h2, 6400, 128, 256);
  gemm_k<64, 64, 16, 4, 4, true><<<dim3(1, 100), 256, 0, stream>>>(
      h2, mW3, mb3, h3, 6400, 64, 128);
  gemm_k<64, 64, 16, 4, 4, true><<<dim3(1, 100), 256, 0, stream>>>(
      h3, mW4, mb4, out, 6400, 5, 64);
}

// Round 8
// 1491.342 us; speedup vs baseline: 19.5510x; 1.0949x over previous
//
#include <hip/hip_runtime.h>
#include <math.h>

namespace {

constexpr int nB = 16, nR = 400, nT = 400, nH = 8, nQ = 64;
constexpr int BH = nB * nH;   // 128
constexpr int HQ = nH * nQ;   // 512
constexpr int KP = 416;       // padded K for bf16 GCN GEMM (13 x 32)

typedef __attribute__((ext_vector_type(8))) short short8;
typedef __attribute__((ext_vector_type(4))) float floatx4;

__device__ __forceinline__ unsigned short f2bf(float f) {
  unsigned int u = __float_as_uint(f);
  unsigned int r = (u + 0x7fffu + ((u >> 16) & 1u)) >> 16;
  return (unsigned short)r;
}

__device__ __forceinline__ void gload16(const void* g, void* l) {
  __builtin_amdgcn_global_load_lds(
      (const __attribute__((address_space(1))) unsigned int*)g,
      (__attribute__((address_space(3))) unsigned int*)l, 16, 0, 0);
}

// ---------------- generic fp32 GEMM: C = act(A@W + bias) ----------------
template<int BM, int BN, int BK, int TM, int TN, bool RELU>
__global__ __launch_bounds__(256) void gemm_k(
    const float* __restrict__ A, const float* __restrict__ W,
    const float* __restrict__ bias,
    float* C, int M, int N, int K)
{
  constexpr int NT = (BM / TM) * (BN / TN);
  static_assert(NT == 256, "block must be 256 threads");
  __shared__ float As[BK][BM + 4];
  __shared__ float Bs[BK][BN + 4];
  const int tid = threadIdx.x;
  const int bm = blockIdx.y * BM;
  const int bn = blockIdx.x * BN;
  const int tx = tid % (BN / TN);
  const int ty = tid / (BN / TN);
  const bool n4ok = ((N & 3) == 0);

  float acc[TM][TN];
#pragma unroll
  for (int i = 0; i < TM; ++i)
#pragma unroll
    for (int j = 0; j < TN; ++j) acc[i][j] = 0.f;

  for (int kt = 0; kt < K; kt += BK) {
#pragma unroll
    for (int i = 0; i < (BM * BK) / (NT * 4); ++i) {
      int flat = (tid + i * NT) * 4;
      int m = flat / BK;
      int k = flat % BK;
      float4 v = *(const float4*)(A + (size_t)(bm + m) * K + kt + k);
      As[k + 0][m] = v.x; As[k + 1][m] = v.y;
      As[k + 2][m] = v.z; As[k + 3][m] = v.w;
    }
#pragma unroll
    for (int i = 0; i < (BK * BN) / (NT * 4); ++i) {
      int flat = (tid + i * NT) * 4;
      int k = flat / BN;
      int n = flat % BN;
      int gn = bn + n;
      float4 v;
      if (n4ok && gn + 3 < N) {
        v = *(const float4*)(W + (size_t)(kt + k) * N + gn);
      } else {
        v.x = (gn + 0 < N) ? W[(size_t)(kt + k) * N + gn + 0] : 0.f;
        v.y = (gn + 1 < N) ? W[(size_t)(kt + k) * N + gn + 1] : 0.f;
        v.z = (gn + 2 < N) ? W[(size_t)(kt + k) * N + gn + 2] : 0.f;
        v.w = (gn + 3 < N) ? W[(size_t)(kt + k) * N + gn + 3] : 0.f;
      }
      *(float4*)&Bs[k][n] = v;
    }
    __syncthreads();
#pragma unroll
    for (int k = 0; k < BK; ++k) {
      float a[TM], b[TN];
#pragma unroll
      for (int i = 0; i < TM; i += 4)
        *(float4*)&a[i] = *(const float4*)&As[k][ty * TM + i];
#pragma unroll
      for (int j = 0; j < TN; j += 4)
        *(float4*)&b[j] = *(const float4*)&Bs[k][tx * TN + j];
#pragma unroll
      for (int i = 0; i < TM; ++i)
#pragma unroll
        for (int j = 0; j < TN; ++j) acc[i][j] += a[i] * b[j];
    }
    __syncthreads();
  }

#pragma unroll
  for (int i = 0; i < TM; ++i) {
    const int gm = bm + ty * TM + i;
    float* crow = C + (size_t)gm * N;
#pragma unroll
    for (int j = 0; j < TN; j += 4) {
      const int gn = bn + tx * TN + j;
      if (n4ok && gn + 3 < N) {
        float4 bv = *(const float4*)(bias + gn);
        float4 v;
        v.x = acc[i][j + 0] + bv.x; v.y = acc[i][j + 1] + bv.y;
        v.z = acc[i][j + 2] + bv.z; v.w = acc[i][j + 3] + bv.w;
        if (RELU) {
          v.x = fmaxf(v.x, 0.f); v.y = fmaxf(v.y, 0.f);
          v.z = fmaxf(v.z, 0.f); v.w = fmaxf(v.w, 0.f);
        }
        *(float4*)(crow + gn) = v;
      } else {
#pragma unroll
        for (int jj = 0; jj < 4; ++jj) {
          int gnn = gn + jj;
          if (gnn < N) {
            float v = acc[i][j + jj] + bias[gnn];
            if (RELU) v = fmaxf(v, 0.f);
            crow[gnn] = v;
          }
        }
      }
    }
  }
}

// ---------------- bf16 MFMA GEMM for GCN layers (128x128 tile, KP=416) --------
__global__ __launch_bounds__(256) void gcn_gemm(
    const unsigned short* __restrict__ A,
    const unsigned short* __restrict__ Bt,
    const float* __restrict__ bias,
    float* __restrict__ C,
    const float* __restrict__ x, int first)
{
  __shared__ __align__(128) unsigned short As[128 * 32];  // 8 KB
  __shared__ __align__(128) unsigned short Bs[128 * 32];  // 8 KB

  const int tid = threadIdx.x;
  const int lane = tid & 63;
  const int wave = tid >> 6;
  const int bm = blockIdx.y * 128;
  const int bn = blockIdx.x * 128;        // covers 512 cols; >=400 is pad
  const int wm = (wave & 1) * 64;
  const int wn = (wave >> 1) * 64;

  floatx4 acc[4][4] = {};

  const int r0 = wave * 32 + (lane >> 2);
  const int c0 = (lane & 3) * 8;
  const unsigned short* Ag0 = A + (size_t)(bm + r0) * KP + c0;
  const unsigned short* Ag1 = A + (size_t)(bm + r0 + 16) * KP + c0;
  int br0 = bn + r0;      if (br0 > 415) br0 = 415;  // zero-pad row of Wt
  int br1 = bn + r0 + 16; if (br1 > 415) br1 = 415;
  const unsigned short* Bg0 = Bt + (size_t)br0 * KP + c0;
  const unsigned short* Bg1 = Bt + (size_t)br1 * KP + c0;
  unsigned short* Al0 = As + (wave * 2) * 512;
  unsigned short* Al1 = As + (wave * 2 + 1) * 512;
  unsigned short* Bl0 = Bs + (wave * 2) * 512;
  unsigned short* Bl1 = Bs + (wave * 2 + 1) * 512;

  const int fr = lane & 15;
  const int fkk = (lane >> 4) * 8;

  for (int kt = 0; kt < KP; kt += 32) {
    gload16(Ag0 + kt, Al0);
    gload16(Ag1 + kt, Al1);
    gload16(Bg0 + kt, Bl0);
    gload16(Bg1 + kt, Bl1);
    __syncthreads();

    short8 a[4], b[4];
#pragma unroll
    for (int mi = 0; mi < 4; ++mi)
      a[mi] = *(const short8*)(As + (wm + mi * 16 + fr) * 32 + fkk);
#pragma unroll
    for (int ni = 0; ni < 4; ++ni)
      b[ni] = *(const short8*)(Bs + (wn + ni * 16 + fr) * 32 + fkk);
#pragma unroll
    for (int mi = 0; mi < 4; ++mi)
#pragma unroll
      for (int ni = 0; ni < 4; ++ni)
        acc[mi][ni] = __builtin_amdgcn_mfma_f32_16x16x32_bf16(
            a[mi], b[ni], acc[mi][ni], 0, 0, 0);
    __syncthreads();
  }

  const int colb = bn + wn + (lane & 15);
  float bv[4];
#pragma unroll
  for (int ni = 0; ni < 4; ++ni) {
    const int col = colb + ni * 16;
    bv[ni] = (col < nT) ? bias[col] : 0.f;
  }

#pragma unroll
  for (int mi = 0; mi < 4; ++mi) {
    const int row0 = bm + wm + mi * 16 + (lane >> 4) * 4;
#pragma unroll
    for (int r = 0; r < 4; ++r) {
      const int gr = row0 + r;
      float* crow = C + (size_t)gr * nT;
      const float* resrow;
      if (first) {
        const int bh = gr / nR;
        const int rr = gr - bh * nR;
        resrow = x + (size_t)(bh >> 3) * (nR * nT) + (size_t)rr * nT;
      } else {
        resrow = crow;
      }
#pragma unroll
      for (int ni = 0; ni < 4; ++ni) {
        const int col = colb + ni * 16;
        if (col < nT)
          crow[col] = fmaxf(acc[mi][ni][r] + bv[ni], 0.f) + resrow[col];
      }
    }
  }
}

// ---------------- W prep: Wt[i][n][k] = bf16(gcn_W[i][k][n]), zero-padded ------
__global__ void wprep_k(const float* __restrict__ W, unsigned short* __restrict__ Wt)
{
  __shared__ float t[32][33];
  const int i = blockIdx.z;
  const int k0 = blockIdx.x * 32;
  const int n0 = blockIdx.y * 32;
  const int tx = threadIdx.x, ty = threadIdx.y;   // 32 x 8
#pragma unroll
  for (int r = 0; r < 32; r += 8) {
    int k = k0 + ty + r, n = n0 + tx;
    t[ty + r][tx] = (k < nT && n < nT) ? W[(size_t)i * nT * nT + (size_t)k * nT + n] : 0.f;
  }
  __syncthreads();
#pragma unroll
  for (int r = 0; r < 32; r += 8) {
    int n = n0 + ty + r, k = k0 + tx;
    Wt[(size_t)i * KP * KP + (size_t)n * KP + k] = f2bf(t[tx][ty + r]);
  }
}

// ---------------- SE gate (gap == 1/R identically) -----------------------------
__global__ void gate_k(const float* __restrict__ w1, const float* __restrict__ b1,
                       const float* __restrict__ w2, const float* __restrict__ b2,
                       float* gate)
{
  if (threadIdx.x == 0 && blockIdx.x == 0) {
    float h1[4];
    const float gap = 1.0f / 400.0f;
#pragma unroll
    for (int i = 0; i < 4; ++i) {
      float s = b1[i];
      for (int h = 0; h < 8; ++h) s += gap * w1[h * 4 + i];
      h1[i] = fmaxf(s, 0.f);
    }
#pragma unroll
    for (int h = 0; h < 8; ++h) {
      float s = b2[h];
      for (int i = 0; i < 4; ++i) s += h1[i] * w2[i * 8 + h];
      gate[h] = 1.f / (1.f + expf(-s));
    }
  }
}

// ---------------- batched QK^T scores: sc = relu((Q@K^T)/8), symmetric ---------
// Q == K, so S is symmetric: only tiles tm <= tn are computed; each block writes
// its tile and the bitwise-identical transpose (float mul commutes).
// Staging: row = lane -> LDS write banks (const+lane)%32, conflict-free (the R6/R7
// transpose-write 8-way conflict is gone). Global reads uncoalesced but L2-hot.
__global__ __launch_bounds__(256) void qkscore_k(
    const float* __restrict__ qk, float* __restrict__ sc)
{
  __shared__ float Qs[64][68];   // Qs[k][m]
  __shared__ float Ks[64][68];   // Ks[k][n]

  const int tm = blockIdx.y;     // m-tile
  const int tn = blockIdx.x;     // n-tile
  if (tm > tn) return;           // symmetry: skip lower triangle (uniform exit)

  const int tid = threadIdx.x;
  const int bh = blockIdx.z;
  const int b = bh >> 3, h = bh & 7;
  const int bm = tm * 64;
  const int bn = tn * 64;
  const float* qkb = qk + (size_t)b * nR * HQ + h * nQ;

  {
    const int row = tid & 63;                 // = lane -> conflict-free LDS writes
#pragma unroll
    for (int p = 0; p < 4; ++p) {
      const int kc = (tid >> 6) + p * 4;      // 0..15
      int gr = bm + row; if (gr > 399) gr = 399;
      float4 v = *(const float4*)(qkb + (size_t)gr * HQ + (kc << 2));
      Qs[kc * 4 + 0][row] = v.x; Qs[kc * 4 + 1][row] = v.y;
      Qs[kc * 4 + 2][row] = v.z; Qs[kc * 4 + 3][row] = v.w;
      int gs = bn + row; if (gs > 399) gs = 399;
      float4 w = *(const float4*)(qkb + (size_t)gs * HQ + (kc << 2));
      Ks[kc * 4 + 0][row] = w.x; Ks[kc * 4 + 1][row] = w.y;
      Ks[kc * 4 + 2][row] = w.z; Ks[kc * 4 + 3][row] = w.w;
    }
  }
  __syncthreads();

  const int tx = tid & 15;    // n/4
  const int ty = tid >> 4;    // m/4
  float acc[4][4] = {};
#pragma unroll 8
  for (int k = 0; k < 64; ++k) {
    float4 a = *(const float4*)&Qs[k][ty * 4];
    float4 bv = *(const float4*)&Ks[k][tx * 4];
    acc[0][0] += a.x * bv.x; acc[0][1] += a.x * bv.y; acc[0][2] += a.x * bv.z; acc[0][3] += a.x * bv.w;
    acc[1][0] += a.y * bv.x; acc[1][1] += a.y * bv.y; acc[1][2] += a.y * bv.z; acc[1][3] += a.y * bv.w;
    acc[2][0] += a.z * bv.x; acc[2][1] += a.z * bv.y; acc[2][2] += a.z * bv.z; acc[2][3] += a.z * bv.w;
    acc[3][0] += a.w * bv.x; acc[3][1] += a.w * bv.y; acc[3][2] += a.w * bv.z; acc[3][3] += a.w * bv.w;
  }

  float* scb = sc + (size_t)bh * nR * 400;

  // direct tile [bm+ty*4+i][bn+tx*4 ..]
  {
    const int gc = bn + tx * 4;
    if (gc < 400) {
#pragma unroll
      for (int i = 0; i < 4; ++i) {
        const int gr = bm + ty * 4 + i;
        if (gr < 400) {
          float4 o;
          o.x = fmaxf(acc[i][0] * 0.125f, 0.f);
          o.y = fmaxf(acc[i][1] * 0.125f, 0.f);
          o.z = fmaxf(acc[i][2] * 0.125f, 0.f);
          o.w = fmaxf(acc[i][3] * 0.125f, 0.f);
          *(float4*)(scb + (size_t)gr * 400 + gc) = o;
        }
      }
    }
  }

  // transposed tile [bn+tx*4+j][bm+ty*4 ..] (skip on diagonal: same tile)
  if (tm != tn) {
    const int gc = bm + ty * 4;
    if (gc < 400) {
#pragma unroll
      for (int j = 0; j < 4; ++j) {
        const int gr = bn + tx * 4 + j;
        if (gr < 400) {
          float4 o;
          o.x = fmaxf(acc[0][j] * 0.125f, 0.f);
          o.y = fmaxf(acc[1][j] * 0.125f, 0.f);
          o.z = fmaxf(acc[2][j] * 0.125f, 0.f);
          o.w = fmaxf(acc[3][j] * 0.125f, 0.f);
          *(float4*)(scb + (size_t)gr * 400 + gc) = o;
        }
      }
    }
  }
}

// ---------------- softmax + gate + stable-rank mask -> sparse adj --------------
__global__ __launch_bounds__(256) void rankadj_k(
    const float* __restrict__ sc, const float* __restrict__ gate,
    float* __restrict__ adjval, int* __restrict__ adjcol)
{
  __shared__ float rowbuf[4][408];

  const int wave = threadIdx.x >> 6;
  const int lane = threadIdx.x & 63;
  const int row = blockIdx.x * 4 + wave;    // 0..51199
  const int bh = row / nR;
  const int r = row - bh * nR;
  const float* srow = sc + (size_t)row * 400;

  float v[7];
  bool valid[7];
#pragma unroll
  for (int it = 0; it < 7; ++it) {
    const int j = lane + it * 64;
    valid[it] = (j < 400);
    v[it] = valid[it] ? srow[j] : 0.f;
  }

  float m = 0.f;
#pragma unroll
  for (int it = 0; it < 7; ++it) m = fmaxf(m, v[it]);
#pragma unroll
  for (int o = 32; o > 0; o >>= 1) m = fmaxf(m, __shfl_xor(m, o));

  float e[7];
  float s = 0.f;
#pragma unroll
  for (int it = 0; it < 7; ++it) {
    e[it] = valid[it] ? expf(v[it] - m) : 0.f;
    s += e[it];
  }
#pragma unroll
  for (int o = 32; o > 0; o >>= 1) s += __shfl_xor(s, o);

  const float g = gate[bh & 7];
  float val[7];
#pragma unroll
  for (int it = 0; it < 7; ++it) val[it] = (e[it] / s) * g;

#pragma unroll
  for (int it = 0; it < 7; ++it)
    if (valid[it]) rowbuf[wave][lane + it * 64] = val[it];
  __syncthreads();

  const int csp[6] = {0, 16, 17, 18, 19, 20};
  float vc[6];
#pragma unroll
  for (int i = 0; i < 6; ++i) vc[i] = rowbuf[wave][csp[i]];
  int rk[6] = {0, 0, 0, 0, 0, 0};
#pragma unroll
  for (int it = 0; it < 7; ++it) {
    if (valid[it]) {
      const int j = lane + it * 64;
      const float vj = val[it];
#pragma unroll
      for (int i = 0; i < 6; ++i)
        rk[i] += (vj < vc[i]) ? 1 : ((vj == vc[i] && j < csp[i]) ? 1 : 0);
    }
  }
#pragma unroll
  for (int i = 0; i < 6; ++i)
#pragma unroll
    for (int o = 32; o > 0; o >>= 1) rk[i] += __shfl_xor(rk[i], o);

  if (lane == 0) {
    const size_t base = (size_t)row * 8;
    bool dup = false;
#pragma unroll
    for (int i = 0; i < 6; ++i) {
      const int p = rk[i];
      adjcol[base + i] = p;
      adjval[base + i] = rowbuf[wave][p];
      dup = dup || (p == r);
    }
    adjcol[base + 6] = r;
    adjval[base + 6] = dup ? 0.f : rowbuf[wave][r];
    adjcol[base + 7] = r;
    adjval[base + 7] = 0.f;
  }
}

// ---------------- sparse msg via LDS-staged feats column-chunks ----------------
__global__ __launch_bounds__(256) void spmsg_k(
    const int* __restrict__ adjcol, const float* __restrict__ adjval,
    const float* __restrict__ feats, const float* __restrict__ x, int first,
    unsigned short* __restrict__ msg)
{
  __shared__ float fs[400 * 36];   // 57.6 KB, row stride 36 floats

  const int tid = threadIdx.x;
  const int bh = blockIdx.y;
  const int c0 = blockIdx.x * 32;
  const float* src = first ? (x + (size_t)(bh >> 3) * (nR * nT))
                           : (feats + (size_t)bh * nR * nT);

  for (int i = tid; i < 3200; i += 256) {
    const int r = i >> 3, c4 = i & 7;
    const int c = c0 + c4 * 4;
    float4 v = {0.f, 0.f, 0.f, 0.f};
    if (c < 400) v = *(const float4*)(src + (size_t)r * nT + c);
    *(float4*)&fs[r * 36 + c4 * 4] = v;
  }
  __syncthreads();

  const int* ac = adjcol + (size_t)bh * nR * 8;
  const float* av = adjval + (size_t)bh * nR * 8;
  for (int i = tid; i < 3200; i += 256) {
    const int r = i >> 3, c4 = i & 7;
    float4 acc = {0.f, 0.f, 0.f, 0.f};
#pragma unroll
    for (int j = 0; j < 7; ++j) {
      const int col = ac[r * 8 + j];
      const float val = av[r * 8 + j];
      float4 v = *(const float4*)&fs[col * 36 + c4 * 4];
      acc.x += val * v.x; acc.y += val * v.y;
      acc.z += val * v.z; acc.w += val * v.w;
    }
    unsigned short* o = msg + ((size_t)bh * nR + r) * KP + c0 + c4 * 4;
    *(ushort4*)o = make_ushort4(f2bf(acc.x), f2bf(acc.y), f2bf(acc.z), f2bf(acc.w));
  }
}

// ---------------- head fusion ---------------------------------------------------
__global__ void hfuse_k(const float* __restrict__ feats, const float* __restrict__ fw,
                        const float* __restrict__ fb, float* __restrict__ fused)
{
  size_t i = (size_t)blockIdx.x * 256 + threadIdx.x;
  constexpr size_t tot4 = (size_t)nB * nR * nT / 4;
  if (i >= tot4) return;
  size_t b = i / (nR * nT / 4);
  size_t rem = i % (nR * nT / 4);
  float fbv = fb[0];
  float4 acc = {fbv, fbv, fbv, fbv};
#pragma unroll
  for (int h = 0; h < nH; ++h) {
    float w = fw[h];
    float4 v = ((const float4*)feats)[(b * nH + h) * (nR * nT / 4) + rem];
    acc.x += w * v.x; acc.y += w * v.y; acc.z += w * v.z; acc.w += w * v.w;
  }
  ((float4*)fused)[i] = acc;
}

}  // namespace

extern "C" void kernel_launch(void* const* d_in, const int* in_sizes, int n_in,
                              void* d_out, int out_size, void* d_ws, size_t ws_size,
                              hipStream_t stream)
{
  (void)in_sizes; (void)n_in; (void)out_size; (void)ws_size;
  const float* x    = (const float*)d_in[0];
  const float* Wk   = (const float*)d_in[1];
  const float* bk   = (const float*)d_in[2];
  const float* seW1 = (const float*)d_in[3];
  const float* seb1 = (const float*)d_in[4];
  const float* seW2 = (const float*)d_in[5];
  const float* seb2 = (const float*)d_in[6];
  const float* gcnW = (const float*)d_in[7];
  const float* gcnb = (const float*)d_in[8];
  const float* fw   = (const float*)d_in[9];
  const float* fb   = (const float*)d_in[10];
  const float* mW1  = (const float*)d_in[11];
  const float* mb1  = (const float*)d_in[12];
  const float* mW2  = (const float*)d_in[13];
  const float* mb2  = (const float*)d_in[14];
  const float* mW3  = (const float*)d_in[15];
  const float* mb3  = (const float*)d_in[16];
  const float* mW4  = (const float*)d_in[17];
  const float* mb4  = (const float*)d_in[18];
  float* out = (float*)d_out;

  // workspace (float units), total ~130.6 MB
  float* ws     = (float*)d_ws;
  float* adjval = ws;
  int*   adjcol = (int*)(adjval + 409600);
  float* gate   = (float*)(adjcol + 409600);
  unsigned short* Wt = (unsigned short*)(gate + 64);          // 8*416*416 shorts
  float* feats  = gate + 64 + (size_t)8 * KP * KP / 2;        // 51200*400 f
  float* scores = feats;                                      // aliases feats (dead until GCN L0)
  float* big    = feats + (size_t)51200 * 400;
  float* qk     = big;                                        // 6400*512 f
  unsigned short* msg = (unsigned short*)big;                 // 51200*416 sh
  float* fused  = big;                                        // aliases dead msg
  float* h1     = fused + (size_t)6400 * 400;
  float* h2     = h1 + (size_t)6400 * 256;
  float* h3     = h2 + (size_t)6400 * 128;

  // 0. gcn_W -> bf16, transposed (n-major), zero-padded to 416x416
  wprep_k<<<dim3(13, 13, 8), dim3(32, 8), 0, stream>>>(gcnW, Wt);

  // 1. qk = x @ Wk + bk
  gemm_k<64, 64, 16, 4, 4, false><<<dim3(8, 100), 256, 0, stream>>>(
      x, Wk, bk, qk, 6400, 512, 400);

  // 2. SE gate
  gate_k<<<1, 64, 0, stream>>>(seW1, seb1, seW2, seb2, gate);

  // 3a. batched symmetric QK^T -> relu -> scores [51200,400] (in feats region)
  qkscore_k<<<dim3(7, 7, 128), 256, 0, stream>>>(qk, scores);

  // 3b. softmax+gate+rank -> 7-sparse adjacency (one wave per row)
  rankadj_k<<<12800, 256, 0, stream>>>(scores, gate, adjval, adjcol);

  // 4. 8x GCN: LDS-gather spmsg + bf16 MFMA GEMM (layer 0 sources x directly)
  for (int i = 0; i < 8; ++i) {
    spmsg_k<<<dim3(13, BH), 256, 0, stream>>>(adjcol, adjval, feats, x,
                                              (i == 0) ? 1 : 0, msg);
    gcn_gemm<<<dim3(4, 400), 256, 0, stream>>>(
        msg, Wt + (size_t)i * KP * KP, gcnb + (size_t)i * nT, feats, x,
        (i == 0) ? 1 : 0);
  }

  // 5. fuse heads
  hfuse_k<<<2500, 256, 0, stream>>>(feats, fw, fb, fused);

  // 6-9. MLP head (fp32)
  gemm_k<64, 64, 16, 4, 4, true><<<dim3(4, 100), 256, 0, stream>>>(
      fused, mW1, mb1, h1, 6400, 256, 400);
  gemm_k<64, 64, 16, 4, 4, true><<<dim3(2, 100), 256, 0, stream>>>(
      h1, mW2, mb2, h2, 6400, 128, 256);
  gemm_k<64, 64, 16, 4, 4, true><<<dim3(1, 100), 256, 0, stream>>>(
      h2, mW3, mb3, h3, 6400, 64, 128);
  gemm_k<64, 64, 16, 4, 4, true><<<dim3(1, 100), 256, 0, stream>>>(
      h3, mW4, mb4, out, 6400, 5, 64);
}

// Round 9
// 1343.138 us; speedup vs baseline: 21.7083x; 1.1103x over previous
//
#include <hip/hip_runtime.h>
#include <math.h>

namespace {

constexpr int nB = 16, nR = 400, nT = 400, nH = 8, nQ = 64;
constexpr int BH = nB * nH;   // 128
constexpr int HQ = nH * nQ;   // 512
constexpr int KP = 416;       // padded K for bf16 GCN GEMM (13 x 32)

typedef __attribute__((ext_vector_type(8))) short short8;
typedef __attribute__((ext_vector_type(4))) float floatx4;

__device__ __forceinline__ unsigned short f2bf(float f) {
  unsigned int u = __float_as_uint(f);
  unsigned int r = (u + 0x7fffu + ((u >> 16) & 1u)) >> 16;
  return (unsigned short)r;
}

__device__ __forceinline__ void gload16(const void* g, void* l) {
  __builtin_amdgcn_global_load_lds(
      (const __attribute__((address_space(1))) unsigned int*)g,
      (__attribute__((address_space(3))) unsigned int*)l, 16, 0, 0);
}

// ---------------- generic fp32 GEMM: C = act(A@W + bias) ----------------
template<int BM, int BN, int BK, int TM, int TN, bool RELU>
__global__ __launch_bounds__(256) void gemm_k(
    const float* __restrict__ A, const float* __restrict__ W,
    const float* __restrict__ bias,
    float* C, int M, int N, int K)
{
  constexpr int NT = (BM / TM) * (BN / TN);
  static_assert(NT == 256, "block must be 256 threads");
  __shared__ float As[BK][BM + 4];
  __shared__ float Bs[BK][BN + 4];
  const int tid = threadIdx.x;
  const int bm = blockIdx.y * BM;
  const int bn = blockIdx.x * BN;
  const int tx = tid % (BN / TN);
  const int ty = tid / (BN / TN);
  const bool n4ok = ((N & 3) == 0);

  float acc[TM][TN];
#pragma unroll
  for (int i = 0; i < TM; ++i)
#pragma unroll
    for (int j = 0; j < TN; ++j) acc[i][j] = 0.f;

  for (int kt = 0; kt < K; kt += BK) {
#pragma unroll
    for (int i = 0; i < (BM * BK) / (NT * 4); ++i) {
      int flat = (tid + i * NT) * 4;
      int m = flat / BK;
      int k = flat % BK;
      float4 v = *(const float4*)(A + (size_t)(bm + m) * K + kt + k);
      As[k + 0][m] = v.x; As[k + 1][m] = v.y;
      As[k + 2][m] = v.z; As[k + 3][m] = v.w;
    }
#pragma unroll
    for (int i = 0; i < (BK * BN) / (NT * 4); ++i) {
      int flat = (tid + i * NT) * 4;
      int k = flat / BN;
      int n = flat % BN;
      int gn = bn + n;
      float4 v;
      if (n4ok && gn + 3 < N) {
        v = *(const float4*)(W + (size_t)(kt + k) * N + gn);
      } else {
        v.x = (gn + 0 < N) ? W[(size_t)(kt + k) * N + gn + 0] : 0.f;
        v.y = (gn + 1 < N) ? W[(size_t)(kt + k) * N + gn + 1] : 0.f;
        v.z = (gn + 2 < N) ? W[(size_t)(kt + k) * N + gn + 2] : 0.f;
        v.w = (gn + 3 < N) ? W[(size_t)(kt + k) * N + gn + 3] : 0.f;
      }
      *(float4*)&Bs[k][n] = v;
    }
    __syncthreads();
#pragma unroll
    for (int k = 0; k < BK; ++k) {
      float a[TM], b[TN];
#pragma unroll
      for (int i = 0; i < TM; i += 4)
        *(float4*)&a[i] = *(const float4*)&As[k][ty * TM + i];
#pragma unroll
      for (int j = 0; j < TN; j += 4)
        *(float4*)&b[j] = *(const float4*)&Bs[k][tx * TN + j];
#pragma unroll
      for (int i = 0; i < TM; ++i)
#pragma unroll
        for (int j = 0; j < TN; ++j) acc[i][j] += a[i] * b[j];
    }
    __syncthreads();
  }

#pragma unroll
  for (int i = 0; i < TM; ++i) {
    const int gm = bm + ty * TM + i;
    float* crow = C + (size_t)gm * N;
#pragma unroll
    for (int j = 0; j < TN; j += 4) {
      const int gn = bn + tx * TN + j;
      if (n4ok && gn + 3 < N) {
        float4 bv = *(const float4*)(bias + gn);
        float4 v;
        v.x = acc[i][j + 0] + bv.x; v.y = acc[i][j + 1] + bv.y;
        v.z = acc[i][j + 2] + bv.z; v.w = acc[i][j + 3] + bv.w;
        if (RELU) {
          v.x = fmaxf(v.x, 0.f); v.y = fmaxf(v.y, 0.f);
          v.z = fmaxf(v.z, 0.f); v.w = fmaxf(v.w, 0.f);
        }
        *(float4*)(crow + gn) = v;
      } else {
#pragma unroll
        for (int jj = 0; jj < 4; ++jj) {
          int gnn = gn + jj;
          if (gnn < N) {
            float v = acc[i][j + jj] + bias[gnn];
            if (RELU) v = fmaxf(v, 0.f);
            crow[gnn] = v;
          }
        }
      }
    }
  }
}

// ---------------- bf16 MFMA GEMM for GCN layers (128x128 tile, KP=416) --------
// Epilogue v2: LDS-bounce (2 passes of 128x64, stride 68) -> coalesced float4
// residual read + float4 store. (R8's per-lane scalar dword epilogue was the
// latency chain: 32 scalar mem-ops/lane over 164 MB of the 222 MB traffic.)
__global__ __launch_bounds__(256) void gcn_gemm(
    const unsigned short* __restrict__ A,
    const unsigned short* __restrict__ Bt,
    const float* __restrict__ bias,
    float* __restrict__ C,
    const float* __restrict__ x, int first)
{
  __shared__ __align__(16) char smem[34816];  // max(As+Bs 16KB, Os 128*68*4)
  unsigned short* As = (unsigned short*)smem;             // 128*32 shorts
  unsigned short* Bs = (unsigned short*)(smem + 8192);    // 128*32 shorts
  float* Os = (float*)smem;                               // [128][68]

  const int tid = threadIdx.x;
  const int lane = tid & 63;
  const int wave = tid >> 6;
  const int bm = blockIdx.y * 128;
  const int bn = blockIdx.x * 128;        // covers 512 cols; >=400 is pad
  const int wm = (wave & 1) * 64;
  const int wn = (wave >> 1) * 64;

  floatx4 acc[4][4] = {};

  const int r0 = wave * 32 + (lane >> 2);
  const int c0 = (lane & 3) * 8;
  const unsigned short* Ag0 = A + (size_t)(bm + r0) * KP + c0;
  const unsigned short* Ag1 = A + (size_t)(bm + r0 + 16) * KP + c0;
  int br0 = bn + r0;      if (br0 > 415) br0 = 415;  // zero-pad row of Wt
  int br1 = bn + r0 + 16; if (br1 > 415) br1 = 415;
  const unsigned short* Bg0 = Bt + (size_t)br0 * KP + c0;
  const unsigned short* Bg1 = Bt + (size_t)br1 * KP + c0;
  unsigned short* Al0 = As + (wave * 2) * 512;
  unsigned short* Al1 = As + (wave * 2 + 1) * 512;
  unsigned short* Bl0 = Bs + (wave * 2) * 512;
  unsigned short* Bl1 = Bs + (wave * 2 + 1) * 512;

  const int fr = lane & 15;
  const int fkk = (lane >> 4) * 8;

  for (int kt = 0; kt < KP; kt += 32) {
    gload16(Ag0 + kt, Al0);
    gload16(Ag1 + kt, Al1);
    gload16(Bg0 + kt, Bl0);
    gload16(Bg1 + kt, Bl1);
    __syncthreads();

    short8 a[4], b[4];
#pragma unroll
    for (int mi = 0; mi < 4; ++mi)
      a[mi] = *(const short8*)(As + (wm + mi * 16 + fr) * 32 + fkk);
#pragma unroll
    for (int ni = 0; ni < 4; ++ni)
      b[ni] = *(const short8*)(Bs + (wn + ni * 16 + fr) * 32 + fkk);
#pragma unroll
    for (int mi = 0; mi < 4; ++mi)
#pragma unroll
      for (int ni = 0; ni < 4; ++ni)
        acc[mi][ni] = __builtin_amdgcn_mfma_f32_16x16x32_bf16(
            a[mi], b[ni], acc[mi][ni], 0, 0, 0);
    __syncthreads();
  }

  // bias per ni (C/D layout: col = lane&15, row = (lane>>4)*4 + reg)
  float bv[4];
#pragma unroll
  for (int ni = 0; ni < 4; ++ni) {
    const int col = bn + wn + ni * 16 + (lane & 15);
    bv[ni] = (col < nT) ? bias[col] : 0.f;
  }

  // 2 passes over 64-col chunks: relu(acc+bias) -> LDS -> float4 residual+store
  for (int p = 0; p < 2; ++p) {
    if (wn == p * 64) {
#pragma unroll
      for (int mi = 0; mi < 4; ++mi)
#pragma unroll
        for (int ni = 0; ni < 4; ++ni)
#pragma unroll
          for (int r = 0; r < 4; ++r) {
            const int row = wm + mi * 16 + (lane >> 4) * 4 + r;
            const int cl = ni * 16 + (lane & 15);
            Os[row * 68 + cl] = fmaxf(acc[mi][ni][r] + bv[ni], 0.f);
          }
    }
    __syncthreads();

    const int cbase = bn + p * 64;
#pragma unroll
    for (int ii = 0; ii < 8; ++ii) {
      const int f = tid + ii * 256;
      const int row = f >> 4;
      const int c4 = (f & 15) << 2;
      const int col = cbase + c4;
      if (col < nT) {
        const int gr = bm + row;
        float4 v = *(const float4*)&Os[row * 68 + c4];
        const float* rrow;
        if (first) {
          const int bh = gr / nR;
          const int rr = gr - bh * nR;
          rrow = x + (size_t)(bh >> 3) * (nR * nT) + (size_t)rr * nT;
        } else {
          rrow = C + (size_t)gr * nT;
        }
        float4 rv = *(const float4*)(rrow + col);
        v.x += rv.x; v.y += rv.y; v.z += rv.z; v.w += rv.w;
        *(float4*)(C + (size_t)gr * nT + col) = v;
      }
    }
    __syncthreads();
  }
}

// ---------------- W prep: Wt[i][n][k] = bf16(gcn_W[i][k][n]), zero-padded ------
__global__ void wprep_k(const float* __restrict__ W, unsigned short* __restrict__ Wt)
{
  __shared__ float t[32][33];
  const int i = blockIdx.z;
  const int k0 = blockIdx.x * 32;
  const int n0 = blockIdx.y * 32;
  const int tx = threadIdx.x, ty = threadIdx.y;   // 32 x 8
#pragma unroll
  for (int r = 0; r < 32; r += 8) {
    int k = k0 + ty + r, n = n0 + tx;
    t[ty + r][tx] = (k < nT && n < nT) ? W[(size_t)i * nT * nT + (size_t)k * nT + n] : 0.f;
  }
  __syncthreads();
#pragma unroll
  for (int r = 0; r < 32; r += 8) {
    int n = n0 + ty + r, k = k0 + tx;
    Wt[(size_t)i * KP * KP + (size_t)n * KP + k] = f2bf(t[tx][ty + r]);
  }
}

// ---------------- SE gate (gap == 1/R identically) -----------------------------
__global__ void gate_k(const float* __restrict__ w1, const float* __restrict__ b1,
                       const float* __restrict__ w2, const float* __restrict__ b2,
                       float* gate)
{
  if (threadIdx.x == 0 && blockIdx.x == 0) {
    float h1[4];
    const float gap = 1.0f / 400.0f;
#pragma unroll
    for (int i = 0; i < 4; ++i) {
      float s = b1[i];
      for (int h = 0; h < 8; ++h) s += gap * w1[h * 4 + i];
      h1[i] = fmaxf(s, 0.f);
    }
#pragma unroll
    for (int h = 0; h < 8; ++h) {
      float s = b2[h];
      for (int i = 0; i < 4; ++i) s += h1[i] * w2[i * 8 + h];
      gate[h] = 1.f / (1.f + expf(-s));
    }
  }
}

// ---------------- batched QK^T scores: sc = relu((Q@K^T)/8), symmetric ---------
__global__ __launch_bounds__(256) void qkscore_k(
    const float* __restrict__ qk, float* __restrict__ sc)
{
  __shared__ float Qs[64][68];   // Qs[k][m]
  __shared__ float Ks[64][68];   // Ks[k][n]

  const int tm = blockIdx.y;     // m-tile
  const int tn = blockIdx.x;     // n-tile
  if (tm > tn) return;           // symmetry: skip lower triangle (uniform exit)

  const int tid = threadIdx.x;
  const int bh = blockIdx.z;
  const int b = bh >> 3, h = bh & 7;
  const int bm = tm * 64;
  const int bn = tn * 64;
  const float* qkb = qk + (size_t)b * nR * HQ + h * nQ;

  {
    const int row = tid & 63;                 // = lane -> conflict-free LDS writes
#pragma unroll
    for (int p = 0; p < 4; ++p) {
      const int kc = (tid >> 6) + p * 4;      // 0..15
      int gr = bm + row; if (gr > 399) gr = 399;
      float4 v = *(const float4*)(qkb + (size_t)gr * HQ + (kc << 2));
      Qs[kc * 4 + 0][row] = v.x; Qs[kc * 4 + 1][row] = v.y;
      Qs[kc * 4 + 2][row] = v.z; Qs[kc * 4 + 3][row] = v.w;
      int gs = bn + row; if (gs > 399) gs = 399;
      float4 w = *(const float4*)(qkb + (size_t)gs * HQ + (kc << 2));
      Ks[kc * 4 + 0][row] = w.x; Ks[kc * 4 + 1][row] = w.y;
      Ks[kc * 4 + 2][row] = w.z; Ks[kc * 4 + 3][row] = w.w;
    }
  }
  __syncthreads();

  const int tx = tid & 15;    // n/4
  const int ty = tid >> 4;    // m/4
  float acc[4][4] = {};
#pragma unroll 8
  for (int k = 0; k < 64; ++k) {
    float4 a = *(const float4*)&Qs[k][ty * 4];
    float4 bv = *(const float4*)&Ks[k][tx * 4];
    acc[0][0] += a.x * bv.x; acc[0][1] += a.x * bv.y; acc[0][2] += a.x * bv.z; acc[0][3] += a.x * bv.w;
    acc[1][0] += a.y * bv.x; acc[1][1] += a.y * bv.y; acc[1][2] += a.y * bv.z; acc[1][3] += a.y * bv.w;
    acc[2][0] += a.z * bv.x; acc[2][1] += a.z * bv.y; acc[2][2] += a.z * bv.z; acc[2][3] += a.z * bv.w;
    acc[3][0] += a.w * bv.x; acc[3][1] += a.w * bv.y; acc[3][2] += a.w * bv.z; acc[3][3] += a.w * bv.w;
  }

  float* scb = sc + (size_t)bh * nR * 400;

  {
    const int gc = bn + tx * 4;
    if (gc < 400) {
#pragma unroll
      for (int i = 0; i < 4; ++i) {
        const int gr = bm + ty * 4 + i;
        if (gr < 400) {
          float4 o;
          o.x = fmaxf(acc[i][0] * 0.125f, 0.f);
          o.y = fmaxf(acc[i][1] * 0.125f, 0.f);
          o.z = fmaxf(acc[i][2] * 0.125f, 0.f);
          o.w = fmaxf(acc[i][3] * 0.125f, 0.f);
          *(float4*)(scb + (size_t)gr * 400 + gc) = o;
        }
      }
    }
  }

  if (tm != tn) {
    const int gc = bm + ty * 4;
    if (gc < 400) {
#pragma unroll
      for (int j = 0; j < 4; ++j) {
        const int gr = bn + tx * 4 + j;
        if (gr < 400) {
          float4 o;
          o.x = fmaxf(acc[0][j] * 0.125f, 0.f);
          o.y = fmaxf(acc[1][j] * 0.125f, 0.f);
          o.z = fmaxf(acc[2][j] * 0.125f, 0.f);
          o.w = fmaxf(acc[3][j] * 0.125f, 0.f);
          *(float4*)(scb + (size_t)gr * 400 + gc) = o;
        }
      }
    }
  }
}

// ---------------- softmax + gate + stable-rank mask -> sparse adj --------------
__global__ __launch_bounds__(256) void rankadj_k(
    const float* __restrict__ sc, const float* __restrict__ gate,
    float* __restrict__ adjval, int* __restrict__ adjcol)
{
  __shared__ float rowbuf[4][408];

  const int wave = threadIdx.x >> 6;
  const int lane = threadIdx.x & 63;
  const int row = blockIdx.x * 4 + wave;    // 0..51199
  const int bh = row / nR;
  const int r = row - bh * nR;
  const float* srow = sc + (size_t)row * 400;

  float v[7];
  bool valid[7];
#pragma unroll
  for (int it = 0; it < 7; ++it) {
    const int j = lane + it * 64;
    valid[it] = (j < 400);
    v[it] = valid[it] ? srow[j] : 0.f;
  }

  float m = 0.f;
#pragma unroll
  for (int it = 0; it < 7; ++it) m = fmaxf(m, v[it]);
#pragma unroll
  for (int o = 32; o > 0; o >>= 1) m = fmaxf(m, __shfl_xor(m, o));

  float e[7];
  float s = 0.f;
#pragma unroll
  for (int it = 0; it < 7; ++it) {
    e[it] = valid[it] ? expf(v[it] - m) : 0.f;
    s += e[it];
  }
#pragma unroll
  for (int o = 32; o > 0; o >>= 1) s += __shfl_xor(s, o);

  const float g = gate[bh & 7];
  float val[7];
#pragma unroll
  for (int it = 0; it < 7; ++it) val[it] = (e[it] / s) * g;

#pragma unroll
  for (int it = 0; it < 7; ++it)
    if (valid[it]) rowbuf[wave][lane + it * 64] = val[it];
  __syncthreads();

  const int csp[6] = {0, 16, 17, 18, 19, 20};
  float vc[6];
#pragma unroll
  for (int i = 0; i < 6; ++i) vc[i] = rowbuf[wave][csp[i]];
  int rk[6] = {0, 0, 0, 0, 0, 0};
#pragma unroll
  for (int it = 0; it < 7; ++it) {
    if (valid[it]) {
      const int j = lane + it * 64;
      const float vj = val[it];
#pragma unroll
      for (int i = 0; i < 6; ++i)
        rk[i] += (vj < vc[i]) ? 1 : ((vj == vc[i] && j < csp[i]) ? 1 : 0);
    }
  }
#pragma unroll
  for (int i = 0; i < 6; ++i)
#pragma unroll
    for (int o = 32; o > 0; o >>= 1) rk[i] += __shfl_xor(rk[i], o);

  if (lane == 0) {
    const size_t base = (size_t)row * 8;
    bool dup = false;
#pragma unroll
    for (int i = 0; i < 6; ++i) {
      const int p = rk[i];
      adjcol[base + i] = p;
      adjval[base + i] = rowbuf[wave][p];
      dup = dup || (p == r);
    }
    adjcol[base + 6] = r;
    adjval[base + 6] = dup ? 0.f : rowbuf[wave][r];
    adjcol[base + 7] = r;
    adjval[base + 7] = 0.f;
  }
}

// ---------------- sparse msg via LDS-staged feats column-chunks ----------------
__global__ __launch_bounds__(256) void spmsg_k(
    const int* __restrict__ adjcol, const float* __restrict__ adjval,
    const float* __restrict__ feats, const float* __restrict__ x, int first,
    unsigned short* __restrict__ msg)
{
  __shared__ float fs[400 * 36];   // 57.6 KB, row stride 36 floats

  const int tid = threadIdx.x;
  const int bh = blockIdx.y;
  const int c0 = blockIdx.x * 32;
  const float* src = first ? (x + (size_t)(bh >> 3) * (nR * nT))
                           : (feats + (size_t)bh * nR * nT);

  for (int i = tid; i < 3200; i += 256) {
    const int r = i >> 3, c4 = i & 7;
    const int c = c0 + c4 * 4;
    float4 v = {0.f, 0.f, 0.f, 0.f};
    if (c < 400) v = *(const float4*)(src + (size_t)r * nT + c);
    *(float4*)&fs[r * 36 + c4 * 4] = v;
  }
  __syncthreads();

  const int* ac = adjcol + (size_t)bh * nR * 8;
  const float* av = adjval + (size_t)bh * nR * 8;
  for (int i = tid; i < 3200; i += 256) {
    const int r = i >> 3, c4 = i & 7;
    float4 acc = {0.f, 0.f, 0.f, 0.f};
#pragma unroll
    for (int j = 0; j < 7; ++j) {
      const int col = ac[r * 8 + j];
      const float val = av[r * 8 + j];
      float4 v = *(const float4*)&fs[col * 36 + c4 * 4];
      acc.x += val * v.x; acc.y += val * v.y;
      acc.z += val * v.z; acc.w += val * v.w;
    }
    unsigned short* o = msg + ((size_t)bh * nR + r) * KP + c0 + c4 * 4;
    *(ushort4*)o = make_ushort4(f2bf(acc.x), f2bf(acc.y), f2bf(acc.z), f2bf(acc.w));
  }
}

// ---------------- head fusion ---------------------------------------------------
__global__ void hfuse_k(const float* __restrict__ feats, const float* __restrict__ fw,
                        const float* __restrict__ fb, float* __restrict__ fused)
{
  size_t i = (size_t)blockIdx.x * 256 + threadIdx.x;
  constexpr size_t tot4 = (size_t)nB * nR * nT / 4;
  if (i >= tot4) return;
  size_t b = i / (nR * nT / 4);
  size_t rem = i % (nR * nT / 4);
  float fbv = fb[0];
  float4 acc = {fbv, fbv, fbv, fbv};
#pragma unroll
  for (int h = 0; h < nH; ++h) {
    float w = fw[h];
    float4 v = ((const float4*)feats)[(b * nH + h) * (nR * nT / 4) + rem];
    acc.x += w * v.x; acc.y += w * v.y; acc.z += w * v.z; acc.w += w * v.w;
  }
  ((float4*)fused)[i] = acc;
}

}  // namespace

extern "C" void kernel_launch(void* const* d_in, const int* in_sizes, int n_in,
                              void* d_out, int out_size, void* d_ws, size_t ws_size,
                              hipStream_t stream)
{
  (void)in_sizes; (void)n_in; (void)out_size; (void)ws_size;
  const float* x    = (const float*)d_in[0];
  const float* Wk   = (const float*)d_in[1];
  const float* bk   = (const float*)d_in[2];
  const float* seW1 = (const float*)d_in[3];
  const float* seb1 = (const float*)d_in[4];
  const float* seW2 = (const float*)d_in[5];
  const float* seb2 = (const float*)d_in[6];
  const float* gcnW = (const float*)d_in[7];
  const float* gcnb = (const float*)d_in[8];
  const float* fw   = (const float*)d_in[9];
  const float* fb   = (const float*)d_in[10];
  const float* mW1  = (const float*)d_in[11];
  const float* mb1  = (const float*)d_in[12];
  const float* mW2  = (const float*)d_in[13];
  const float* mb2  = (const float*)d_in[14];
  const float* mW3  = (const float*)d_in[15];
  const float* mb3  = (const float*)d_in[16];
  const float* mW4  = (const float*)d_in[17];
  const float* mb4  = (const float*)d_in[18];
  float* out = (float*)d_out;

  // workspace (float units), total ~130.6 MB
  float* ws     = (float*)d_ws;
  float* adjval = ws;
  int*   adjcol = (int*)(adjval + 409600);
  float* gate   = (float*)(adjcol + 409600);
  unsigned short* Wt = (unsigned short*)(gate + 64);          // 8*416*416 shorts
  float* feats  = gate + 64 + (size_t)8 * KP * KP / 2;        // 51200*400 f
  float* scores = feats;                                      // aliases feats (dead until GCN L0)
  float* big    = feats + (size_t)51200 * 400;
  float* qk     = big;                                        // 6400*512 f
  unsigned short* msg = (unsigned short*)big;                 // 51200*416 sh
  float* fused  = big;                                        // aliases dead msg
  float* h1     = fused + (size_t)6400 * 400;
  float* h2     = h1 + (size_t)6400 * 256;
  float* h3     = h2 + (size_t)6400 * 128;

  // 0. gcn_W -> bf16, transposed (n-major), zero-padded to 416x416
  wprep_k<<<dim3(13, 13, 8), dim3(32, 8), 0, stream>>>(gcnW, Wt);

  // 1. qk = x @ Wk + bk
  gemm_k<64, 64, 16, 4, 4, false><<<dim3(8, 100), 256, 0, stream>>>(
      x, Wk, bk, qk, 6400, 512, 400);

  // 2. SE gate
  gate_k<<<1, 64, 0, stream>>>(seW1, seb1, seW2, seb2, gate);

  // 3a. batched symmetric QK^T -> relu -> scores [51200,400] (in feats region)
  qkscore_k<<<dim3(7, 7, 128), 256, 0, stream>>>(qk, scores);

  // 3b. softmax+gate+rank -> 7-sparse adjacency (one wave per row)
  rankadj_k<<<12800, 256, 0, stream>>>(scores, gate, adjval, adjcol);

  // 4. 8x GCN: LDS-gather spmsg + bf16 MFMA GEMM (layer 0 sources x directly)
  for (int i = 0; i < 8; ++i) {
    spmsg_k<<<dim3(13, BH), 256, 0, stream>>>(adjcol, adjval, feats, x,
                                              (i == 0) ? 1 : 0, msg);
    gcn_gemm<<<dim3(4, 400), 256, 0, stream>>>(
        msg, Wt + (size_t)i * KP * KP, gcnb + (size_t)i * nT, feats, x,
        (i == 0) ? 1 : 0);
  }

  // 5. fuse heads
  hfuse_k<<<2500, 256, 0, stream>>>(feats, fw, fb, fused);

  // 6-9. MLP head (fp32)
  gemm_k<64, 64, 16, 4, 4, true><<<dim3(4, 100), 256, 0, stream>>>(
      fused, mW1, mb1, h1, 6400, 256, 400);
  gemm_k<64, 64, 16, 4, 4, true><<<dim3(2, 100), 256, 0, stream>>>(
      h1, mW2, mb2, h2, 6400, 128, 256);
  gemm_k<64, 64, 16, 4, 4, true><<<dim3(1, 100), 256, 0, stream>>>(
      h2, mW3, mb3, h3, 6400, 64, 128);
  gemm_k<64, 64, 16, 4, 4, true><<<dim3(1, 100), 256, 0, stream>>>(
      h3, mW4, mb4, out, 6400, 5, 64);
}

// Round 10
// 1290.208 us; speedup vs baseline: 22.5989x; 1.0410x over previous
//
#include <hip/hip_runtime.h>
#include <math.h>

namespace {

constexpr int nB = 16, nR = 400, nT = 400, nH = 8, nQ = 64;
constexpr int BH = nB * nH;   // 128
constexpr int HQ = nH * nQ;   // 512
constexpr int KP = 416;       // padded K for bf16 GCN GEMM (13 x 32)

typedef __attribute__((ext_vector_type(8))) short short8;
typedef __attribute__((ext_vector_type(4))) float floatx4;

__device__ __forceinline__ unsigned short f2bf(float f) {
  unsigned int u = __float_as_uint(f);
  unsigned int r = (u + 0x7fffu + ((u >> 16) & 1u)) >> 16;
  return (unsigned short)r;
}

__device__ __forceinline__ void gload16(const void* g, void* l) {
  __builtin_amdgcn_global_load_lds(
      (const __attribute__((address_space(1))) unsigned int*)g,
      (__attribute__((address_space(3))) unsigned int*)l, 16, 0, 0);
}

// ---------------- generic fp32 GEMM: C = act(A@W + bias) ----------------
template<int BM, int BN, int BK, int TM, int TN, bool RELU>
__global__ __launch_bounds__(256) void gemm_k(
    const float* __restrict__ A, const float* __restrict__ W,
    const float* __restrict__ bias,
    float* C, int M, int N, int K)
{
  constexpr int NT = (BM / TM) * (BN / TN);
  static_assert(NT == 256, "block must be 256 threads");
  __shared__ float As[BK][BM + 4];
  __shared__ float Bs[BK][BN + 4];
  const int tid = threadIdx.x;
  const int bm = blockIdx.y * BM;
  const int bn = blockIdx.x * BN;
  const int tx = tid % (BN / TN);
  const int ty = tid / (BN / TN);
  const bool n4ok = ((N & 3) == 0);

  float acc[TM][TN];
#pragma unroll
  for (int i = 0; i < TM; ++i)
#pragma unroll
    for (int j = 0; j < TN; ++j) acc[i][j] = 0.f;

  for (int kt = 0; kt < K; kt += BK) {
#pragma unroll
    for (int i = 0; i < (BM * BK) / (NT * 4); ++i) {
      int flat = (tid + i * NT) * 4;
      int m = flat / BK;
      int k = flat % BK;
      float4 v = *(const float4*)(A + (size_t)(bm + m) * K + kt + k);
      As[k + 0][m] = v.x; As[k + 1][m] = v.y;
      As[k + 2][m] = v.z; As[k + 3][m] = v.w;
    }
#pragma unroll
    for (int i = 0; i < (BK * BN) / (NT * 4); ++i) {
      int flat = (tid + i * NT) * 4;
      int k = flat / BN;
      int n = flat % BN;
      int gn = bn + n;
      float4 v;
      if (n4ok && gn + 3 < N) {
        v = *(const float4*)(W + (size_t)(kt + k) * N + gn);
      } else {
        v.x = (gn + 0 < N) ? W[(size_t)(kt + k) * N + gn + 0] : 0.f;
        v.y = (gn + 1 < N) ? W[(size_t)(kt + k) * N + gn + 1] : 0.f;
        v.z = (gn + 2 < N) ? W[(size_t)(kt + k) * N + gn + 2] : 0.f;
        v.w = (gn + 3 < N) ? W[(size_t)(kt + k) * N + gn + 3] : 0.f;
      }
      *(float4*)&Bs[k][n] = v;
    }
    __syncthreads();
#pragma unroll
    for (int k = 0; k < BK; ++k) {
      float a[TM], b[TN];
#pragma unroll
      for (int i = 0; i < TM; i += 4)
        *(float4*)&a[i] = *(const float4*)&As[k][ty * TM + i];
#pragma unroll
      for (int j = 0; j < TN; j += 4)
        *(float4*)&b[j] = *(const float4*)&Bs[k][tx * TN + j];
#pragma unroll
      for (int i = 0; i < TM; ++i)
#pragma unroll
        for (int j = 0; j < TN; ++j) acc[i][j] += a[i] * b[j];
    }
    __syncthreads();
  }

#pragma unroll
  for (int i = 0; i < TM; ++i) {
    const int gm = bm + ty * TM + i;
    float* crow = C + (size_t)gm * N;
#pragma unroll
    for (int j = 0; j < TN; j += 4) {
      const int gn = bn + tx * TN + j;
      if (n4ok && gn + 3 < N) {
        float4 bv = *(const float4*)(bias + gn);
        float4 v;
        v.x = acc[i][j + 0] + bv.x; v.y = acc[i][j + 1] + bv.y;
        v.z = acc[i][j + 2] + bv.z; v.w = acc[i][j + 3] + bv.w;
        if (RELU) {
          v.x = fmaxf(v.x, 0.f); v.y = fmaxf(v.y, 0.f);
          v.z = fmaxf(v.z, 0.f); v.w = fmaxf(v.w, 0.f);
        }
        *(float4*)(crow + gn) = v;
      } else {
#pragma unroll
        for (int jj = 0; jj < 4; ++jj) {
          int gnn = gn + jj;
          if (gnn < N) {
            float v = acc[i][j + jj] + bias[gnn];
            if (RELU) v = fmaxf(v, 0.f);
            crow[gnn] = v;
          }
        }
      }
    }
  }
}

// ---------------- bf16 MFMA GEMM for GCN layers (128x128 tile, KP=416) --------
// Epilogue v3: 64x64 LDS-bounce passes (Os 17.4 KB aliases the 16 KB staging)
// -> LDS block 17408 B -> 5 blocks/CU (R9's 34.8 KB Os capped it at 4).
__global__ __launch_bounds__(256) void gcn_gemm(
    const unsigned short* __restrict__ A,
    const unsigned short* __restrict__ Bt,
    const float* __restrict__ bias,
    float* __restrict__ C,
    const float* __restrict__ x, int first)
{
  __shared__ __align__(16) char smem[17408];  // max(As+Bs 16 KB, Os 64*68*4)
  unsigned short* As = (unsigned short*)smem;             // 128*32 shorts
  unsigned short* Bs = (unsigned short*)(smem + 8192);    // 128*32 shorts
  float* Os = (float*)smem;                               // [64][68]

  const int tid = threadIdx.x;
  const int lane = tid & 63;
  const int wave = tid >> 6;
  const int bm = blockIdx.y * 128;
  const int bn = blockIdx.x * 128;        // covers 512 cols; >=400 is pad
  const int wm = (wave & 1) * 64;
  const int wn = (wave >> 1) * 64;

  floatx4 acc[4][4] = {};

  const int r0 = wave * 32 + (lane >> 2);
  const int c0 = (lane & 3) * 8;
  const unsigned short* Ag0 = A + (size_t)(bm + r0) * KP + c0;
  const unsigned short* Ag1 = A + (size_t)(bm + r0 + 16) * KP + c0;
  int br0 = bn + r0;      if (br0 > 415) br0 = 415;  // zero-pad row of Wt
  int br1 = bn + r0 + 16; if (br1 > 415) br1 = 415;
  const unsigned short* Bg0 = Bt + (size_t)br0 * KP + c0;
  const unsigned short* Bg1 = Bt + (size_t)br1 * KP + c0;
  unsigned short* Al0 = As + (wave * 2) * 512;
  unsigned short* Al1 = As + (wave * 2 + 1) * 512;
  unsigned short* Bl0 = Bs + (wave * 2) * 512;
  unsigned short* Bl1 = Bs + (wave * 2 + 1) * 512;

  const int fr = lane & 15;
  const int fkk = (lane >> 4) * 8;

  for (int kt = 0; kt < KP; kt += 32) {
    gload16(Ag0 + kt, Al0);
    gload16(Ag1 + kt, Al1);
    gload16(Bg0 + kt, Bl0);
    gload16(Bg1 + kt, Bl1);
    __syncthreads();

    short8 a[4], b[4];
#pragma unroll
    for (int mi = 0; mi < 4; ++mi)
      a[mi] = *(const short8*)(As + (wm + mi * 16 + fr) * 32 + fkk);
#pragma unroll
    for (int ni = 0; ni < 4; ++ni)
      b[ni] = *(const short8*)(Bs + (wn + ni * 16 + fr) * 32 + fkk);
#pragma unroll
    for (int mi = 0; mi < 4; ++mi)
#pragma unroll
      for (int ni = 0; ni < 4; ++ni)
        acc[mi][ni] = __builtin_amdgcn_mfma_f32_16x16x32_bf16(
            a[mi], b[ni], acc[mi][ni], 0, 0, 0);
    __syncthreads();
  }

  // bias per ni (C/D layout: col = lane&15, row = (lane>>4)*4 + reg)
  float bv[4];
#pragma unroll
  for (int ni = 0; ni < 4; ++ni) {
    const int col = bn + wn + ni * 16 + (lane & 15);
    bv[ni] = (col < nT) ? bias[col] : 0.f;
  }

  // 4 passes (2 row-halves x 2 col-halves): owning wave writes relu(acc+bias)
  // into Os[64][68]; all 4 waves cooperatively residual+store float4.
  for (int rh = 0; rh < 2; ++rh) {
    for (int p = 0; p < 2; ++p) {
      if (wm == rh * 64 && wn == p * 64) {
#pragma unroll
        for (int mi = 0; mi < 4; ++mi)
#pragma unroll
          for (int ni = 0; ni < 4; ++ni)
#pragma unroll
            for (int r = 0; r < 4; ++r) {
              const int lrow = mi * 16 + (lane >> 4) * 4 + r;
              const int cl = ni * 16 + (lane & 15);
              Os[lrow * 68 + cl] = fmaxf(acc[mi][ni][r] + bv[ni], 0.f);
            }
      }
      __syncthreads();

      const int rbase = bm + rh * 64;
      const int cbase = bn + p * 64;
#pragma unroll
      for (int ii = 0; ii < 4; ++ii) {
        const int f = tid + ii * 256;
        const int row = f >> 4;
        const int c4 = (f & 15) << 2;
        const int col = cbase + c4;
        if (col < nT) {
          const int gr = rbase + row;
          float4 v = *(const float4*)&Os[row * 68 + c4];
          const float* rrow;
          if (first) {
            const int bh = gr / nR;
            const int rr = gr - bh * nR;
            rrow = x + (size_t)(bh >> 3) * (nR * nT) + (size_t)rr * nT;
          } else {
            rrow = C + (size_t)gr * nT;
          }
          float4 rv = *(const float4*)(rrow + col);
          v.x += rv.x; v.y += rv.y; v.z += rv.z; v.w += rv.w;
          *(float4*)(C + (size_t)gr * nT + col) = v;
        }
      }
      __syncthreads();
    }
  }
}

// ---------------- W prep: Wt[i][n][k] = bf16(gcn_W[i][k][n]), zero-padded ------
__global__ void wprep_k(const float* __restrict__ W, unsigned short* __restrict__ Wt)
{
  __shared__ float t[32][33];
  const int i = blockIdx.z;
  const int k0 = blockIdx.x * 32;
  const int n0 = blockIdx.y * 32;
  const int tx = threadIdx.x, ty = threadIdx.y;   // 32 x 8
#pragma unroll
  for (int r = 0; r < 32; r += 8) {
    int k = k0 + ty + r, n = n0 + tx;
    t[ty + r][tx] = (k < nT && n < nT) ? W[(size_t)i * nT * nT + (size_t)k * nT + n] : 0.f;
  }
  __syncthreads();
#pragma unroll
  for (int r = 0; r < 32; r += 8) {
    int n = n0 + ty + r, k = k0 + tx;
    Wt[(size_t)i * KP * KP + (size_t)n * KP + k] = f2bf(t[tx][ty + r]);
  }
}

// ---------------- SE gate (gap == 1/R identically) -----------------------------
__global__ void gate_k(const float* __restrict__ w1, const float* __restrict__ b1,
                       const float* __restrict__ w2, const float* __restrict__ b2,
                       float* gate)
{
  if (threadIdx.x == 0 && blockIdx.x == 0) {
    float h1[4];
    const float gap = 1.0f / 400.0f;
#pragma unroll
    for (int i = 0; i < 4; ++i) {
      float s = b1[i];
      for (int h = 0; h < 8; ++h) s += gap * w1[h * 4 + i];
      h1[i] = fmaxf(s, 0.f);
    }
#pragma unroll
    for (int h = 0; h < 8; ++h) {
      float s = b2[h];
      for (int i = 0; i < 4; ++i) s += h1[i] * w2[i * 8 + h];
      gate[h] = 1.f / (1.f + expf(-s));
    }
  }
}

// ---------------- batched QK^T scores: sc = relu((Q@K^T)/8), symmetric ---------
__global__ __launch_bounds__(256) void qkscore_k(
    const float* __restrict__ qk, float* __restrict__ sc)
{
  __shared__ float Qs[64][68];   // Qs[k][m]
  __shared__ float Ks[64][68];   // Ks[k][n]

  const int tm = blockIdx.y;     // m-tile
  const int tn = blockIdx.x;     // n-tile
  if (tm > tn) return;           // symmetry: skip lower triangle (uniform exit)

  const int tid = threadIdx.x;
  const int bh = blockIdx.z;
  const int b = bh >> 3, h = bh & 7;
  const int bm = tm * 64;
  const int bn = tn * 64;
  const float* qkb = qk + (size_t)b * nR * HQ + h * nQ;

  {
    const int row = tid & 63;                 // = lane -> conflict-free LDS writes
#pragma unroll
    for (int p = 0; p < 4; ++p) {
      const int kc = (tid >> 6) + p * 4;      // 0..15
      int gr = bm + row; if (gr > 399) gr = 399;
      float4 v = *(const float4*)(qkb + (size_t)gr * HQ + (kc << 2));
      Qs[kc * 4 + 0][row] = v.x; Qs[kc * 4 + 1][row] = v.y;
      Qs[kc * 4 + 2][row] = v.z; Qs[kc * 4 + 3][row] = v.w;
      int gs = bn + row; if (gs > 399) gs = 399;
      float4 w = *(const float4*)(qkb + (size_t)gs * HQ + (kc << 2));
      Ks[kc * 4 + 0][row] = w.x; Ks[kc * 4 + 1][row] = w.y;
      Ks[kc * 4 + 2][row] = w.z; Ks[kc * 4 + 3][row] = w.w;
    }
  }
  __syncthreads();

  const int tx = tid & 15;    // n/4
  const int ty = tid >> 4;    // m/4
  float acc[4][4] = {};
#pragma unroll 8
  for (int k = 0; k < 64; ++k) {
    float4 a = *(const float4*)&Qs[k][ty * 4];
    float4 bv = *(const float4*)&Ks[k][tx * 4];
    acc[0][0] += a.x * bv.x; acc[0][1] += a.x * bv.y; acc[0][2] += a.x * bv.z; acc[0][3] += a.x * bv.w;
    acc[1][0] += a.y * bv.x; acc[1][1] += a.y * bv.y; acc[1][2] += a.y * bv.z; acc[1][3] += a.y * bv.w;
    acc[2][0] += a.z * bv.x; acc[2][1] += a.z * bv.y; acc[2][2] += a.z * bv.z; acc[2][3] += a.z * bv.w;
    acc[3][0] += a.w * bv.x; acc[3][1] += a.w * bv.y; acc[3][2] += a.w * bv.z; acc[3][3] += a.w * bv.w;
  }

  float* scb = sc + (size_t)bh * nR * 400;

  {
    const int gc = bn + tx * 4;
    if (gc < 400) {
#pragma unroll
      for (int i = 0; i < 4; ++i) {
        const int gr = bm + ty * 4 + i;
        if (gr < 400) {
          float4 o;
          o.x = fmaxf(acc[i][0] * 0.125f, 0.f);
          o.y = fmaxf(acc[i][1] * 0.125f, 0.f);
          o.z = fmaxf(acc[i][2] * 0.125f, 0.f);
          o.w = fmaxf(acc[i][3] * 0.125f, 0.f);
          *(float4*)(scb + (size_t)gr * 400 + gc) = o;
        }
      }
    }
  }

  if (tm != tn) {
    const int gc = bm + ty * 4;
    if (gc < 400) {
#pragma unroll
      for (int j = 0; j < 4; ++j) {
        const int gr = bn + tx * 4 + j;
        if (gr < 400) {
          float4 o;
          o.x = fmaxf(acc[0][j] * 0.125f, 0.f);
          o.y = fmaxf(acc[1][j] * 0.125f, 0.f);
          o.z = fmaxf(acc[2][j] * 0.125f, 0.f);
          o.w = fmaxf(acc[3][j] * 0.125f, 0.f);
          *(float4*)(scb + (size_t)gr * 400 + gc) = o;
        }
      }
    }
  }
}

// ---------------- softmax + gate + stable-rank mask -> sparse adj --------------
__global__ __launch_bounds__(256) void rankadj_k(
    const float* __restrict__ sc, const float* __restrict__ gate,
    float* __restrict__ adjval, int* __restrict__ adjcol)
{
  __shared__ float rowbuf[4][408];

  const int wave = threadIdx.x >> 6;
  const int lane = threadIdx.x & 63;
  const int row = blockIdx.x * 4 + wave;    // 0..51199
  const int bh = row / nR;
  const int r = row - bh * nR;
  const float* srow = sc + (size_t)row * 400;

  float v[7];
  bool valid[7];
#pragma unroll
  for (int it = 0; it < 7; ++it) {
    const int j = lane + it * 64;
    valid[it] = (j < 400);
    v[it] = valid[it] ? srow[j] : 0.f;
  }

  float m = 0.f;
#pragma unroll
  for (int it = 0; it < 7; ++it) m = fmaxf(m, v[it]);
#pragma unroll
  for (int o = 32; o > 0; o >>= 1) m = fmaxf(m, __shfl_xor(m, o));

  float e[7];
  float s = 0.f;
#pragma unroll
  for (int it = 0; it < 7; ++it) {
    e[it] = valid[it] ? expf(v[it] - m) : 0.f;
    s += e[it];
  }
#pragma unroll
  for (int o = 32; o > 0; o >>= 1) s += __shfl_xor(s, o);

  const float g = gate[bh & 7];
  float val[7];
#pragma unroll
  for (int it = 0; it < 7; ++it) val[it] = (e[it] / s) * g;

#pragma unroll
  for (int it = 0; it < 7; ++it)
    if (valid[it]) rowbuf[wave][lane + it * 64] = val[it];
  __syncthreads();

  const int csp[6] = {0, 16, 17, 18, 19, 20};
  float vc[6];
#pragma unroll
  for (int i = 0; i < 6; ++i) vc[i] = rowbuf[wave][csp[i]];
  int rk[6] = {0, 0, 0, 0, 0, 0};
#pragma unroll
  for (int it = 0; it < 7; ++it) {
    if (valid[it]) {
      const int j = lane + it * 64;
      const float vj = val[it];
#pragma unroll
      for (int i = 0; i < 6; ++i)
        rk[i] += (vj < vc[i]) ? 1 : ((vj == vc[i] && j < csp[i]) ? 1 : 0);
    }
  }
#pragma unroll
  for (int i = 0; i < 6; ++i)
#pragma unroll
    for (int o = 32; o > 0; o >>= 1) rk[i] += __shfl_xor(rk[i], o);

  if (lane == 0) {
    const size_t base = (size_t)row * 8;
    bool dup = false;
#pragma unroll
    for (int i = 0; i < 6; ++i) {
      const int p = rk[i];
      adjcol[base + i] = p;
      adjval[base + i] = rowbuf[wave][p];
      dup = dup || (p == r);
    }
    adjcol[base + 6] = r;
    adjval[base + 6] = dup ? 0.f : rowbuf[wave][r];
    adjcol[base + 7] = r;
    adjval[base + 7] = 0.f;
  }
}

// ---------------- sparse msg via LDS-staged feats column-chunks ----------------
// v2: 16-col chunks (grid 26 x 128), fs stride 20 -> LDS 32 KB -> 5 blocks/CU
// (R9's 57.6 KB capped it at 2 blocks/CU; latency-bound gather needs waves).
__global__ __launch_bounds__(256) void spmsg_k(
    const int* __restrict__ adjcol, const float* __restrict__ adjval,
    const float* __restrict__ feats, const float* __restrict__ x, int first,
    unsigned short* __restrict__ msg)
{
  __shared__ float fs[400 * 20];   // 32 KB, row stride 20 floats

  const int tid = threadIdx.x;
  const int bh = blockIdx.y;
  const int c0 = blockIdx.x * 16;
  const float* src = first ? (x + (size_t)(bh >> 3) * (nR * nT))
                           : (feats + (size_t)bh * nR * nT);

  for (int i = tid; i < 1600; i += 256) {
    const int r = i >> 2, cg = i & 3;
    const int c = c0 + cg * 4;
    float4 v = {0.f, 0.f, 0.f, 0.f};
    if (c < 400) v = *(const float4*)(src + (size_t)r * nT + c);
    *(float4*)&fs[r * 20 + cg * 4] = v;
  }
  __syncthreads();

  const int* ac = adjcol + (size_t)bh * nR * 8;
  const float* av = adjval + (size_t)bh * nR * 8;
  for (int i = tid; i < 1600; i += 256) {
    const int r = i >> 2, cg = i & 3;
    float4 acc = {0.f, 0.f, 0.f, 0.f};
#pragma unroll
    for (int j = 0; j < 7; ++j) {
      const int col = ac[r * 8 + j];
      const float val = av[r * 8 + j];
      float4 v = *(const float4*)&fs[col * 20 + cg * 4];
      acc.x += val * v.x; acc.y += val * v.y;
      acc.z += val * v.z; acc.w += val * v.w;
    }
    unsigned short* o = msg + ((size_t)bh * nR + r) * KP + c0 + cg * 4;
    *(ushort4*)o = make_ushort4(f2bf(acc.x), f2bf(acc.y), f2bf(acc.z), f2bf(acc.w));
  }
}

// ---------------- head fusion ---------------------------------------------------
__global__ void hfuse_k(const float* __restrict__ feats, const float* __restrict__ fw,
                        const float* __restrict__ fb, float* __restrict__ fused)
{
  size_t i = (size_t)blockIdx.x * 256 + threadIdx.x;
  constexpr size_t tot4 = (size_t)nB * nR * nT / 4;
  if (i >= tot4) return;
  size_t b = i / (nR * nT / 4);
  size_t rem = i % (nR * nT / 4);
  float fbv = fb[0];
  float4 acc = {fbv, fbv, fbv, fbv};
#pragma unroll
  for (int h = 0; h < nH; ++h) {
    float w = fw[h];
    float4 v = ((const float4*)feats)[(b * nH + h) * (nR * nT / 4) + rem];
    acc.x += w * v.x; acc.y += w * v.y; acc.z += w * v.z; acc.w += w * v.w;
  }
  ((float4*)fused)[i] = acc;
}

}  // namespace

extern "C" void kernel_launch(void* const* d_in, const int* in_sizes, int n_in,
                              void* d_out, int out_size, void* d_ws, size_t ws_size,
                              hipStream_t stream)
{
  (void)in_sizes; (void)n_in; (void)out_size; (void)ws_size;
  const float* x    = (const float*)d_in[0];
  const float* Wk   = (const float*)d_in[1];
  const float* bk   = (const float*)d_in[2];
  const float* seW1 = (const float*)d_in[3];
  const float* seb1 = (const float*)d_in[4];
  const float* seW2 = (const float*)d_in[5];
  const float* seb2 = (const float*)d_in[6];
  const float* gcnW = (const float*)d_in[7];
  const float* gcnb = (const float*)d_in[8];
  const float* fw   = (const float*)d_in[9];
  const float* fb   = (const float*)d_in[10];
  const float* mW1  = (const float*)d_in[11];
  const float* mb1  = (const float*)d_in[12];
  const float* mW2  = (const float*)d_in[13];
  const float* mb2  = (const float*)d_in[14];
  const float* mW3  = (const float*)d_in[15];
  const float* mb3  = (const float*)d_in[16];
  const float* mW4  = (const float*)d_in[17];
  const float* mb4  = (const float*)d_in[18];
  float* out = (float*)d_out;

  // workspace (float units), total ~130.6 MB
  float* ws     = (float*)d_ws;
  float* adjval = ws;
  int*   adjcol = (int*)(adjval + 409600);
  float* gate   = (float*)(adjcol + 409600);
  unsigned short* Wt = (unsigned short*)(gate + 64);          // 8*416*416 shorts
  float* feats  = gate + 64 + (size_t)8 * KP * KP / 2;        // 51200*400 f
  float* scores = feats;                                      // aliases feats (dead until GCN L0)
  float* big    = feats + (size_t)51200 * 400;
  float* qk     = big;                                        // 6400*512 f
  unsigned short* msg = (unsigned short*)big;                 // 51200*416 sh
  float* fused  = big;                                        // aliases dead msg
  float* h1     = fused + (size_t)6400 * 400;
  float* h2     = h1 + (size_t)6400 * 256;
  float* h3     = h2 + (size_t)6400 * 128;

  // 0. gcn_W -> bf16, transposed (n-major), zero-padded to 416x416
  wprep_k<<<dim3(13, 13, 8), dim3(32, 8), 0, stream>>>(gcnW, Wt);

  // 1. qk = x @ Wk + bk
  gemm_k<64, 64, 16, 4, 4, false><<<dim3(8, 100), 256, 0, stream>>>(
      x, Wk, bk, qk, 6400, 512, 400);

  // 2. SE gate
  gate_k<<<1, 64, 0, stream>>>(seW1, seb1, seW2, seb2, gate);

  // 3a. batched symmetric QK^T -> relu -> scores [51200,400] (in feats region)
  qkscore_k<<<dim3(7, 7, 128), 256, 0, stream>>>(qk, scores);

  // 3b. softmax+gate+rank -> 7-sparse adjacency (one wave per row)
  rankadj_k<<<12800, 256, 0, stream>>>(scores, gate, adjval, adjcol);

  // 4. 8x GCN: LDS-gather spmsg + bf16 MFMA GEMM (layer 0 sources x directly)
  for (int i = 0; i < 8; ++i) {
    spmsg_k<<<dim3(26, BH), 256, 0, stream>>>(adjcol, adjval, feats, x,
                                              (i == 0) ? 1 : 0, msg);
    gcn_gemm<<<dim3(4, 400), 256, 0, stream>>>(
        msg, Wt + (size_t)i * KP * KP, gcnb + (size_t)i * nT, feats, x,
        (i == 0) ? 1 : 0);
  }

  // 5. fuse heads
  hfuse_k<<<2500, 256, 0, stream>>>(feats, fw, fb, fused);

  // 6-9. MLP head (fp32)
  gemm_k<64, 64, 16, 4, 4, true><<<dim3(4, 100), 256, 0, stream>>>(
      fused, mW1, mb1, h1, 6400, 256, 400);
  gemm_k<64, 64, 16, 4, 4, true><<<dim3(2, 100), 256, 0, stream>>>(
      h1, mW2, mb2, h2, 6400, 128, 256);
  gemm_k<64, 64, 16, 4, 4, true><<<dim3(1, 100), 256, 0, stream>>>(
      h2, mW3, mb3, h3, 6400, 64, 128);
  gemm_k<64, 64, 16, 4, 4, true><<<dim3(1, 100), 256, 0, stream>>>(
      h3, mW4, mb4, out, 6400, 5, 64);
}